// Round 8
// baseline (630.720 us; speedup 1.0000x reference)
//
#include <hip/hip_runtime.h>
#include <hip/hip_fp16.h>

typedef unsigned short u16;
typedef unsigned int   u32;
typedef _Float16 h2 __attribute__((ext_vector_type(2)));

#define N_NODES 100000
#define N_EDGES 1600000
#define IN_DIM  128
#define HID_DIM 32
#define OUT_DIM 32

#define BK   128                 // cols per bucket
#define NBC  782                 // buckets per channel = ceil(100000/128)
#define NBT  (3 * NBC)           // 2346 total buckets

#define PB    96                 // binning blocks (3E = 96*50000 exactly); fewer blocks
                                 // -> ~21-entry (170B) scatter runs -> ~1.7x write amp
                                 // (PB=256 gave 64B runs -> 3.4x amp, 131MB writes)
#define BINB  1024               // binning block size (16 waves)
#define CHUNK 50000              // edges per binning block
#define SC_N  (NBT * PB)         // 225216 scan elements (multiple of 8)
#define SC_CHUNK 2048
#define SC_G  ((SC_N + SC_CHUNK - 1) / SC_CHUNK)   // 110
#define CAP  3072                // max edges/bucket in LDS; actual max ~2250
#define GN4  ((N_NODES * 4 + 255) / 256) // 1563 blocks for 4-threads-per-node kernels
#define MM2  ((N_NODES + 63) / 64)       // 1563 matmul blocks/channel (64 nodes/block)

#define KEYB 4                   // row-bucket bits: row>>13 in 0..12 (fits 4 bits)
#define NKEY (BK << KEYB)        // 2048 sort keys: (cl<<4) | (row>>13)

// final ofs value without materializing scan3: ofs(m) = m ? rp1[m] + bs[(m-1)>>11] : 0
__device__ inline int ofs_at(const int* __restrict__ rp1, const int* __restrict__ bs, int m) {
    return m ? rp1[m] + bs[(m - 1) >> 11] : 0;
}

// ---------------- phase 1: per-block bucket histogram ----------------

__global__ void binhist_kernel(const int* __restrict__ ei0, const int* __restrict__ ei1,
                               const int* __restrict__ ei2, int* __restrict__ hist_t) {
    __shared__ int hloc[NBT];
    for (int i = threadIdx.x; i < NBT; i += blockDim.x) hloc[i] = 0;
    __syncthreads();
    int b = blockIdx.x;
    int beg = b * CHUNK, end = beg + CHUNK;
    for (int e = beg + threadIdx.x; e < end; e += blockDim.x) {
        int c = (e >= 2 * N_EDGES) ? 2 : (e >= N_EDGES ? 1 : 0);
        const int* ei = (c == 0) ? ei0 : (c == 1) ? ei1 : ei2;
        int col = ei[N_EDGES + (e - c * N_EDGES)];
        atomicAdd(&hloc[c * NBC + (col >> 7)], 1);
    }
    __syncthreads();
    for (int g = threadIdx.x; g < NBT; g += blockDim.x)
        hist_t[g * PB + b] = hloc[g];
}

// ---------------- phase 2: 2-kernel scan over hist_t[SC_N] -> rp1 (+blocksum) ----

__global__ void scan1_kernel(const int* __restrict__ counts, int* __restrict__ rp1,
                             int* __restrict__ blocksum) {
    __shared__ int wsum[4];
    int tid = threadIdx.x;
    int base = blockIdx.x * SC_CHUNK + tid * 8;
    int vals[8];
    int tsum = 0;
    if (base < SC_N) {          // SC_N multiple of 8 -> all-or-nothing per thread
        int4 v0 = *(const int4*)(counts + base);
        int4 v1 = *(const int4*)(counts + base + 4);
        vals[0] = v0.x; vals[1] = v0.y; vals[2] = v0.z; vals[3] = v0.w;
        vals[4] = v1.x; vals[5] = v1.y; vals[6] = v1.z; vals[7] = v1.w;
#pragma unroll
        for (int k = 0; k < 8; k++) tsum += vals[k];
    } else {
#pragma unroll
        for (int k = 0; k < 8; k++) vals[k] = 0;
    }
    int lane = tid & 63, wave = tid >> 6;
    int x = tsum;
    for (int d = 1; d < 64; d <<= 1) {
        int t = __shfl_up(x, d, 64);
        if (lane >= d) x += t;
    }
    if (lane == 63) wsum[wave] = x;
    __syncthreads();
    int woff = 0;
    for (int w = 0; w < wave; w++) woff += wsum[w];
    int run = woff + x - tsum;
    if (base < SC_N) {
#pragma unroll
        for (int k = 0; k < 8; k++) {
            run += vals[k];
            rp1[base + k + 1] = run;
        }
    }
    if (tid == blockDim.x - 1) blocksum[blockIdx.x] = woff + x;
    if (blockIdx.x == 0 && tid == 0) rp1[0] = 0;
}

// single block, loops over n entries in chunks of 256 with carry
__global__ void scan2_kernel(int* __restrict__ blocksum, int n) {
    __shared__ int wsum[4];
    int tid = threadIdx.x;
    int lane = tid & 63, wave = tid >> 6;
    int carry = 0;
    for (int base = 0; base < n; base += 256) {
        int i = base + tid;
        int v = (i < n) ? blocksum[i] : 0;
        int x = v;
        for (int d = 1; d < 64; d <<= 1) {
            int t = __shfl_up(x, d, 64);
            if (lane >= d) x += t;
        }
        if (lane == 63) wsum[wave] = x;
        __syncthreads();
        int woff = 0;
        for (int w = 0; w < wave; w++) woff += wsum[w];
        int total = wsum[0] + wsum[1] + wsum[2] + wsum[3];
        if (i < n) blocksum[i] = carry + woff + x - v;   // exclusive
        carry += total;
        __syncthreads();
    }
}

// ---------------- phase 3: binning scatter (no global atomics) ----------------
// entry: x = row | (colLow<<17), y = ea bits (fp32)

__global__ void binscatter_kernel(const int* __restrict__ ei0, const int* __restrict__ ei1,
                                  const int* __restrict__ ei2,
                                  const float* __restrict__ ea0, const float* __restrict__ ea1,
                                  const float* __restrict__ ea2,
                                  const int* __restrict__ rp1, const int* __restrict__ bsum,
                                  int2* __restrict__ stg) {
    __shared__ int base_l[NBT];
    int b = blockIdx.x;
    for (int g = threadIdx.x; g < NBT; g += blockDim.x)
        base_l[g] = ofs_at(rp1, bsum, g * PB + b);
    __syncthreads();
    int beg = b * CHUNK, end = beg + CHUNK;
    for (int e = beg + threadIdx.x; e < end; e += blockDim.x) {
        int c = (e >= 2 * N_EDGES) ? 2 : (e >= N_EDGES ? 1 : 0);
        int le = e - c * N_EDGES;
        const int* ei = (c == 0) ? ei0 : (c == 1) ? ei1 : ei2;
        const float* ea = (c == 0) ? ea0 : (c == 1) ? ea1 : ea2;
        int row = ei[le];
        int col = ei[N_EDGES + le];
        int g = c * NBC + (col >> 7);
        int slot = atomicAdd(&base_l[g], 1);   // LDS atomic, block-local
        stg[slot] = make_int2(row | ((col & 127) << 17), __float_as_int(ea[le]));
    }
}

// ---------------- phase 4: per-bucket counting sort -> packed CSR + dinv + row_ptr ----
// csr entry: row(17b) | fp16(ea*dinv[col]) sans sign bit (15b).
// Sort key = (cl<<4)|(row>>13): within each col, edges ordered by gathered-row to 8k
// granularity -> gather kernels sweep rows monotonically -> L2-window locality.

__global__ void bucket_sort_kernel(const int2* __restrict__ stg, const int* __restrict__ rp1,
                                   const int* __restrict__ bsum,
                                   u32* __restrict__ csr,
                                   float* __restrict__ dinv, int* __restrict__ row_ptr) {
    __shared__ int2 buf[CAP];          // 24 KB
    __shared__ int hist[NKEY];         // 8 KB; becomes exclusive prefix in-place
    __shared__ int fill[NKEY];         // 8 KB
    __shared__ float deg[BK];
    __shared__ float dl[BK];
    __shared__ int wsum[4];
    int tid = threadIdx.x;
    int g = blockIdx.x;
    int c = g / NBC;
    int colBase = (g % NBC) << 7;
    for (int i = tid; i < NKEY; i += 256) { hist[i] = 0; fill[i] = 0; }
    if (tid < BK) deg[tid] = 1.0f;     // deg: self-loop
    __syncthreads();
    int beg = ofs_at(rp1, bsum, g * PB);
    int end = (g == NBT - 1) ? 3 * N_EDGES : ofs_at(rp1, bsum, (g + 1) * PB);
    int cnt = end - beg;
    if (cnt > CAP) cnt = CAP;          // never hit for this input
    for (int i = tid; i < cnt; i += blockDim.x) {
        int2 p = stg[beg + i];
        buf[i] = p;
        int cl = (p.x >> 17) & 127;
        int row = p.x & 0x1FFFF;
        atomicAdd(&hist[(cl << KEYB) | (row >> 13)], 1);
        atomicAdd(&deg[cl], __int_as_float(p.y));
    }
    __syncthreads();
    // exclusive scan of hist[NKEY] in place (8 entries/thread, wave scan of sums)
    int base8 = tid * 8;
    int v[8]; int tsum = 0;
#pragma unroll
    for (int k = 0; k < 8; k++) { v[k] = hist[base8 + k]; tsum += v[k]; }
    int lane = tid & 63, wave = tid >> 6;
    int xs = tsum;
    for (int d = 1; d < 64; d <<= 1) {
        int tt = __shfl_up(xs, d, 64);
        if (lane >= d) xs += tt;
    }
    if (lane == 63) wsum[wave] = xs;
    __syncthreads();
    int woff = 0;
    for (int w = 0; w < wave; w++) woff += wsum[w];
    int run = woff + xs - tsum;        // exclusive prefix of this thread's first key
#pragma unroll
    for (int k = 0; k < 8; k++) { int t2 = v[k]; hist[base8 + k] = run; run += t2; }
    if (tid < BK) dl[tid] = rsqrtf(deg[tid]);    // deg >= 1
    __syncthreads();                   // hist (prefix) + dl ready for all threads
    for (int i = tid; i < cnt; i += blockDim.x) {
        int2 p = buf[i];
        int cl = (p.x >> 17) & 127;
        int row = p.x & 0x1FFFF;
        int key = (cl << KEYB) | (row >> 13);
        int r = atomicAdd(&fill[key], 1);
        float vv = __int_as_float(p.y) * dl[cl];  // in [0,1): fp16 sign bit = 0
        __half h = __float2half(vv);
        u32 hb = (u32)(*(u16*)&h) & 0x7FFF;
        csr[beg + hist[key] + r] = (u32)row | (hb << 17);
    }
    int col = colBase + tid;
    if (tid < BK && col < N_NODES) {
        dinv[(size_t)c * N_NODES + col] = dl[tid];
        row_ptr[(size_t)c * N_NODES + col] = beg + hist[tid << KEYB];   // LOCAL col idx
    }
    if (g == NBT - 1 && tid == 0) row_ptr[3 * N_NODES] = 3 * N_EDGES;
}

// ---------------- fp16 helpers ----------------

__device__ inline u32 pack_half2(float a, float b) {
    __half2 h = __floats2half2_rn(a, b);
    union { __half2 h; u32 u; } cv; cv.h = h;
    return cv.u;
}

__device__ inline float2 unpack_half2(u32 u) {
    union { u32 u; __half2 h; } cv; cv.u = u;
    return __half22float2(cv.h);
}

__device__ inline float val15(u32 meta) {       // decode 15-bit fp16 payload
    return unpack_half2(meta >> 17).x;          // high half = 0, ignored
}

// v_dot2_f32_f16: a.x*b.x + a.y*b.y + c, fp32 accumulate (f16 products exact in f32)
__device__ inline float fdot2h(u32 a, u32 b, float c) {
    union { u32 u; h2 h; } ca, cb; ca.u = a; cb.u = b;
    return __builtin_amdgcn_fdot2(ca.h, cb.h, c, false);
}

// ---------------- matmul (3 channels): x_c[N,128] @ W_c[128,32], scale by dinv, fp16 ----

__global__ void matmul_in3_kernel(const float* __restrict__ x0, const float* __restrict__ x1,
                                  const float* __restrict__ x2,
                                  const float* __restrict__ W0, const float* __restrict__ W1,
                                  const float* __restrict__ W2,
                                  const float* __restrict__ dinv,
                                  u16* __restrict__ h3) {
    __shared__ u32 Ws2[(IN_DIM / 2) * HID_DIM];   // 8 KB: [jp][d] = half2(W[2jp][d],W[2jp+1][d])
    int c = blockIdx.x / MM2;
    int lb = blockIdx.x % MM2;
    const float* x = (c == 0) ? x0 : (c == 1) ? x1 : x2;
    const float* W = (c == 0) ? W0 : (c == 1) ? W1 : W2;
    for (int i = threadIdx.x; i < (IN_DIM / 2) * HID_DIM; i += blockDim.x) {
        int d = i & 31, jp = i >> 5;
        Ws2[i] = pack_half2(W[(2 * jp) * HID_DIM + d], W[(2 * jp + 1) * HID_DIM + d]);
    }
    __syncthreads();
    int t = threadIdx.x & 7;          // output dim slice 4t..4t+3
    int grp = threadIdx.x >> 3;       // 0..31
    int v0 = lb * 64 + grp * 2;       // 2 consecutive nodes
    if (v0 >= N_NODES) return;        // N_NODES even -> all-or-nothing per thread
    float a[2][4];
#pragma unroll
    for (int k = 0; k < 2; k++)
#pragma unroll
        for (int d = 0; d < 4; d++) a[k][d] = 0.f;
    const float* xr0 = x + (size_t)v0 * IN_DIM;
    const float* xr1 = xr0 + IN_DIM;
#pragma unroll 4
    for (int q = 0; q < 32; q++) {    // 4 K per iter (jp = 2q, 2q+1)
        float4 xv0 = *(const float4*)(xr0 + 4 * q);
        float4 xv1 = *(const float4*)(xr1 + 4 * q);
        u32 p00 = pack_half2(xv0.x, xv0.y), p01 = pack_half2(xv0.z, xv0.w);
        u32 p10 = pack_half2(xv1.x, xv1.y), p11 = pack_half2(xv1.z, xv1.w);
        uint4 wA = *(const uint4*)&Ws2[(2 * q) * HID_DIM + 4 * t];
        uint4 wB = *(const uint4*)&Ws2[(2 * q + 1) * HID_DIM + 4 * t];
        a[0][0] = fdot2h(p00, wA.x, a[0][0]); a[0][1] = fdot2h(p00, wA.y, a[0][1]);
        a[0][2] = fdot2h(p00, wA.z, a[0][2]); a[0][3] = fdot2h(p00, wA.w, a[0][3]);
        a[0][0] = fdot2h(p01, wB.x, a[0][0]); a[0][1] = fdot2h(p01, wB.y, a[0][1]);
        a[0][2] = fdot2h(p01, wB.z, a[0][2]); a[0][3] = fdot2h(p01, wB.w, a[0][3]);
        a[1][0] = fdot2h(p10, wA.x, a[1][0]); a[1][1] = fdot2h(p10, wA.y, a[1][1]);
        a[1][2] = fdot2h(p10, wA.z, a[1][2]); a[1][3] = fdot2h(p10, wA.w, a[1][3]);
        a[1][0] = fdot2h(p11, wB.x, a[1][0]); a[1][1] = fdot2h(p11, wB.y, a[1][1]);
        a[1][2] = fdot2h(p11, wB.z, a[1][2]); a[1][3] = fdot2h(p11, wB.w, a[1][3]);
    }
#pragma unroll
    for (int k = 0; k < 2; k++) {
        float s = dinv[(size_t)c * N_NODES + v0 + k];
        uint2 pk = make_uint2(pack_half2(a[k][0] * s, a[k][1] * s),
                              pack_half2(a[k][2] * s, a[k][3] * s));
        *(uint2*)(h3 + ((size_t)c * N_NODES + v0 + k) * HID_DIM + 4 * t) = pk;
    }
}

// ---------------- matmul (3 channels): hmix[N,32] @ Wo_c[32,32], scale by dinv, fp16 ----

__global__ void matmul_hid3_kernel(const float* __restrict__ hmix,
                                   const float* __restrict__ Wo0, const float* __restrict__ Wo1,
                                   const float* __restrict__ Wo2,
                                   const float* __restrict__ dinv,
                                   u16* __restrict__ h23) {
    __shared__ u32 Ws2[(HID_DIM / 2) * OUT_DIM];  // 2 KB
    int c = blockIdx.x / MM2;
    int lb = blockIdx.x % MM2;
    const float* Wo = (c == 0) ? Wo0 : (c == 1) ? Wo1 : Wo2;
    for (int i = threadIdx.x; i < (HID_DIM / 2) * OUT_DIM; i += blockDim.x) {
        int d = i & 31, jp = i >> 5;
        Ws2[i] = pack_half2(Wo[(2 * jp) * OUT_DIM + d], Wo[(2 * jp + 1) * OUT_DIM + d]);
    }
    __syncthreads();
    int t = threadIdx.x & 7;
    int grp = threadIdx.x >> 3;
    int v0 = lb * 64 + grp * 2;
    if (v0 >= N_NODES) return;
    float a[2][4];
#pragma unroll
    for (int k = 0; k < 2; k++)
#pragma unroll
        for (int d = 0; d < 4; d++) a[k][d] = 0.f;
    const float* hr0 = hmix + (size_t)v0 * HID_DIM;
    const float* hr1 = hr0 + HID_DIM;
#pragma unroll
    for (int q = 0; q < 8; q++) {
        float4 xv0 = *(const float4*)(hr0 + 4 * q);
        float4 xv1 = *(const float4*)(hr1 + 4 * q);
        u32 p00 = pack_half2(xv0.x, xv0.y), p01 = pack_half2(xv0.z, xv0.w);
        u32 p10 = pack_half2(xv1.x, xv1.y), p11 = pack_half2(xv1.z, xv1.w);
        uint4 wA = *(const uint4*)&Ws2[(2 * q) * OUT_DIM + 4 * t];
        uint4 wB = *(const uint4*)&Ws2[(2 * q + 1) * OUT_DIM + 4 * t];
        a[0][0] = fdot2h(p00, wA.x, a[0][0]); a[0][1] = fdot2h(p00, wA.y, a[0][1]);
        a[0][2] = fdot2h(p00, wA.z, a[0][2]); a[0][3] = fdot2h(p00, wA.w, a[0][3]);
        a[0][0] = fdot2h(p01, wB.x, a[0][0]); a[0][1] = fdot2h(p01, wB.y, a[0][1]);
        a[0][2] = fdot2h(p01, wB.z, a[0][2]); a[0][3] = fdot2h(p01, wB.w, a[0][3]);
        a[1][0] = fdot2h(p10, wA.x, a[1][0]); a[1][1] = fdot2h(p10, wA.y, a[1][1]);
        a[1][2] = fdot2h(p10, wA.z, a[1][2]); a[1][3] = fdot2h(p10, wA.w, a[1][3]);
        a[1][0] = fdot2h(p11, wB.x, a[1][0]); a[1][1] = fdot2h(p11, wB.y, a[1][1]);
        a[1][2] = fdot2h(p11, wB.z, a[1][2]); a[1][3] = fdot2h(p11, wB.w, a[1][3]);
    }
#pragma unroll
    for (int k = 0; k < 2; k++) {
        float s = dinv[(size_t)c * N_NODES + v0 + k];
        uint2 pk = make_uint2(pack_half2(a[k][0] * s, a[k][1] * s),
                              pack_half2(a[k][2] * s, a[k][3] * s));
        *(uint2*)(h23 + ((size_t)c * N_NODES + v0 + k) * OUT_DIM + 4 * t) = pk;
    }
}

// ---------------- fused layer-1 gather (3 channels) + attention combine ----------------
// 4 lanes/node, 8 dims/lane (uint4 = 16B row loads).  Edge loop unrolled x4.

__global__ void gather_combine_kernel(const int* __restrict__ row_ptr,
                                      const u32* __restrict__ csr,
                                      const u16* __restrict__ h3,
                                      const float* __restrict__ dinv,
                                      const float* __restrict__ b0,
                                      const float* __restrict__ b1,
                                      const float* __restrict__ b2,
                                      const float* __restrict__ att_w,
                                      float* __restrict__ hmix,
                                      float* __restrict__ wout) {
    int gid = blockIdx.x * blockDim.x + threadIdx.x;
    int v = gid >> 2;
    int t = gid & 3;
    if (v >= N_NODES) return;
    float4 wv0 = *(const float4*)(att_w + t * 8);
    float4 wv1 = *(const float4*)(att_w + t * 8 + 4);
    float e[3][8];
    float coef[3];
#pragma unroll
    for (int c = 0; c < 3; c++) {
        const u16* h = h3 + (size_t)c * N_NODES * HID_DIM;
        const float* bb = (c == 0) ? b0 : (c == 1) ? b1 : b2;
        int beg = row_ptr[c * N_NODES + v], end = row_ptr[c * N_NODES + v + 1];
        float a[8];
#pragma unroll
        for (int k = 0; k < 8; k++) a[k] = 0.f;
        int ee = beg;
        for (; ee + 4 <= end; ee += 4) {
            u32 m0 = csr[ee], m1 = csr[ee + 1], m2 = csr[ee + 2], m3 = csr[ee + 3];
            uint4 u0 = *(const uint4*)(h + (size_t)(m0 & 0x1FFFF) * HID_DIM + 8 * t);
            uint4 u1 = *(const uint4*)(h + (size_t)(m1 & 0x1FFFF) * HID_DIM + 8 * t);
            uint4 u2 = *(const uint4*)(h + (size_t)(m2 & 0x1FFFF) * HID_DIM + 8 * t);
            uint4 u3 = *(const uint4*)(h + (size_t)(m3 & 0x1FFFF) * HID_DIM + 8 * t);
            float vl0 = val15(m0), vl1 = val15(m1), vl2 = val15(m2), vl3 = val15(m3);
            float2 f;
            f = unpack_half2(u0.x); a[0] += vl0 * f.x; a[1] += vl0 * f.y;
            f = unpack_half2(u0.y); a[2] += vl0 * f.x; a[3] += vl0 * f.y;
            f = unpack_half2(u0.z); a[4] += vl0 * f.x; a[5] += vl0 * f.y;
            f = unpack_half2(u0.w); a[6] += vl0 * f.x; a[7] += vl0 * f.y;
            f = unpack_half2(u1.x); a[0] += vl1 * f.x; a[1] += vl1 * f.y;
            f = unpack_half2(u1.y); a[2] += vl1 * f.x; a[3] += vl1 * f.y;
            f = unpack_half2(u1.z); a[4] += vl1 * f.x; a[5] += vl1 * f.y;
            f = unpack_half2(u1.w); a[6] += vl1 * f.x; a[7] += vl1 * f.y;
            f = unpack_half2(u2.x); a[0] += vl2 * f.x; a[1] += vl2 * f.y;
            f = unpack_half2(u2.y); a[2] += vl2 * f.x; a[3] += vl2 * f.y;
            f = unpack_half2(u2.z); a[4] += vl2 * f.x; a[5] += vl2 * f.y;
            f = unpack_half2(u2.w); a[6] += vl2 * f.x; a[7] += vl2 * f.y;
            f = unpack_half2(u3.x); a[0] += vl3 * f.x; a[1] += vl3 * f.y;
            f = unpack_half2(u3.y); a[2] += vl3 * f.x; a[3] += vl3 * f.y;
            f = unpack_half2(u3.z); a[4] += vl3 * f.x; a[5] += vl3 * f.y;
            f = unpack_half2(u3.w); a[6] += vl3 * f.x; a[7] += vl3 * f.y;
        }
        for (; ee < end; ee++) {
            u32 m = csr[ee];
            float vl = val15(m);
            uint4 u = *(const uint4*)(h + (size_t)(m & 0x1FFFF) * HID_DIM + 8 * t);
            float2 f;
            f = unpack_half2(u.x); a[0] += vl * f.x; a[1] += vl * f.y;
            f = unpack_half2(u.y); a[2] += vl * f.x; a[3] += vl * f.y;
            f = unpack_half2(u.z); a[4] += vl * f.x; a[5] += vl * f.y;
            f = unpack_half2(u.w); a[6] += vl * f.x; a[7] += vl * f.y;
        }
        float s = dinv[(size_t)c * N_NODES + v];   // self-loop: s^2*h[v] = s*h3s[v]
        uint4 u = *(const uint4*)(h + (size_t)v * HID_DIM + 8 * t);
        float2 f0 = unpack_half2(u.x), f1 = unpack_half2(u.y);
        float2 f2 = unpack_half2(u.z), f3 = unpack_half2(u.w);
        float4 bv0 = *(const float4*)(bb + t * 8);
        float4 bv1 = *(const float4*)(bb + t * 8 + 4);
        e[c][0] = fmaxf(a[0] + s * f0.x + bv0.x, 0.f);
        e[c][1] = fmaxf(a[1] + s * f0.y + bv0.y, 0.f);
        e[c][2] = fmaxf(a[2] + s * f1.x + bv0.z, 0.f);
        e[c][3] = fmaxf(a[3] + s * f1.y + bv0.w, 0.f);
        e[c][4] = fmaxf(a[4] + s * f2.x + bv1.x, 0.f);
        e[c][5] = fmaxf(a[5] + s * f2.y + bv1.y, 0.f);
        e[c][6] = fmaxf(a[6] + s * f3.x + bv1.z, 0.f);
        e[c][7] = fmaxf(a[7] + s * f3.y + bv1.w, 0.f);
        float dot = e[c][0] * wv0.x + e[c][1] * wv0.y + e[c][2] * wv0.z + e[c][3] * wv0.w
                  + e[c][4] * wv1.x + e[c][5] * wv1.y + e[c][6] * wv1.z + e[c][7] * wv1.w;
        dot += __shfl_xor(dot, 1, 64);
        dot += __shfl_xor(dot, 2, 64);   // all 4 lanes of the group hold the full dot
        float lr = (dot > 0.0f) ? dot : 0.01f * dot;
        coef[c] = expf(lr);
    }
    float inv = 1.0f / (coef[0] + coef[1] + coef[2]);
    float w0 = coef[0] * inv, w1 = coef[1] * inv, w2 = coef[2] * inv;
    if (t == 0) {
        wout[v] = w0;
        wout[N_NODES + v] = w1;
        wout[2 * N_NODES + v] = w2;
    }
    float4 r0, r1;
    r0.x = w0 * e[0][0] + w1 * e[1][0] + w2 * e[2][0];
    r0.y = w0 * e[0][1] + w1 * e[1][1] + w2 * e[2][1];
    r0.z = w0 * e[0][2] + w1 * e[1][2] + w2 * e[2][2];
    r0.w = w0 * e[0][3] + w1 * e[1][3] + w2 * e[2][3];
    r1.x = w0 * e[0][4] + w1 * e[1][4] + w2 * e[2][4];
    r1.y = w0 * e[0][5] + w1 * e[1][5] + w2 * e[2][5];
    r1.z = w0 * e[0][6] + w1 * e[1][6] + w2 * e[2][6];
    r1.w = w0 * e[0][7] + w1 * e[1][7] + w2 * e[2][7];
    *(float4*)(hmix + (size_t)v * HID_DIM + t * 8) = r0;
    *(float4*)(hmix + (size_t)v * HID_DIM + t * 8 + 4) = r1;
}

// ---------------- fused layer-2 gather (3 channels) + self-loops + biases -> out ----

__global__ void gather_out_kernel(const int* __restrict__ row_ptr,
                                  const u32* __restrict__ csr,
                                  const u16* __restrict__ h23,
                                  const float* __restrict__ dinv,
                                  const float* __restrict__ bo0,
                                  const float* __restrict__ bo1,
                                  const float* __restrict__ bo2,
                                  float* __restrict__ out) {
    int gid = blockIdx.x * blockDim.x + threadIdx.x;
    int v = gid >> 2;
    int t = gid & 3;
    if (v >= N_NODES) return;
    float4 p0 = *(const float4*)(bo0 + t * 8);
    float4 p1 = *(const float4*)(bo0 + t * 8 + 4);
    float4 q0 = *(const float4*)(bo1 + t * 8);
    float4 q1 = *(const float4*)(bo1 + t * 8 + 4);
    float4 s0 = *(const float4*)(bo2 + t * 8);
    float4 s1 = *(const float4*)(bo2 + t * 8 + 4);
    float a[8];
    a[0] = p0.x + q0.x + s0.x; a[1] = p0.y + q0.y + s0.y;
    a[2] = p0.z + q0.z + s0.z; a[3] = p0.w + q0.w + s0.w;
    a[4] = p1.x + q1.x + s1.x; a[5] = p1.y + q1.y + s1.y;
    a[6] = p1.z + q1.z + s1.z; a[7] = p1.w + q1.w + s1.w;
#pragma unroll
    for (int c = 0; c < 3; c++) {
        const u16* h2m = h23 + (size_t)c * N_NODES * OUT_DIM;
        int beg = row_ptr[c * N_NODES + v], end = row_ptr[c * N_NODES + v + 1];
        int ee = beg;
        for (; ee + 4 <= end; ee += 4) {
            u32 m0 = csr[ee], m1 = csr[ee + 1], m2 = csr[ee + 2], m3 = csr[ee + 3];
            uint4 u0 = *(const uint4*)(h2m + (size_t)(m0 & 0x1FFFF) * OUT_DIM + 8 * t);
            uint4 u1 = *(const uint4*)(h2m + (size_t)(m1 & 0x1FFFF) * OUT_DIM + 8 * t);
            uint4 u2 = *(const uint4*)(h2m + (size_t)(m2 & 0x1FFFF) * OUT_DIM + 8 * t);
            uint4 u3 = *(const uint4*)(h2m + (size_t)(m3 & 0x1FFFF) * OUT_DIM + 8 * t);
            float vl0 = val15(m0), vl1 = val15(m1), vl2 = val15(m2), vl3 = val15(m3);
            float2 f;
            f = unpack_half2(u0.x); a[0] += vl0 * f.x; a[1] += vl0 * f.y;
            f = unpack_half2(u0.y); a[2] += vl0 * f.x; a[3] += vl0 * f.y;
            f = unpack_half2(u0.z); a[4] += vl0 * f.x; a[5] += vl0 * f.y;
            f = unpack_half2(u0.w); a[6] += vl0 * f.x; a[7] += vl0 * f.y;
            f = unpack_half2(u1.x); a[0] += vl1 * f.x; a[1] += vl1 * f.y;
            f = unpack_half2(u1.y); a[2] += vl1 * f.x; a[3] += vl1 * f.y;
            f = unpack_half2(u1.z); a[4] += vl1 * f.x; a[5] += vl1 * f.y;
            f = unpack_half2(u1.w); a[6] += vl1 * f.x; a[7] += vl1 * f.y;
            f = unpack_half2(u2.x); a[0] += vl2 * f.x; a[1] += vl2 * f.y;
            f = unpack_half2(u2.y); a[2] += vl2 * f.x; a[3] += vl2 * f.y;
            f = unpack_half2(u2.z); a[4] += vl2 * f.x; a[5] += vl2 * f.y;
            f = unpack_half2(u2.w); a[6] += vl2 * f.x; a[7] += vl2 * f.y;
            f = unpack_half2(u3.x); a[0] += vl3 * f.x; a[1] += vl3 * f.y;
            f = unpack_half2(u3.y); a[2] += vl3 * f.x; a[3] += vl3 * f.y;
            f = unpack_half2(u3.z); a[4] += vl3 * f.x; a[5] += vl3 * f.y;
            f = unpack_half2(u3.w); a[6] += vl3 * f.x; a[7] += vl3 * f.y;
        }
        for (; ee < end; ee++) {
            u32 m = csr[ee];
            float vl = val15(m);
            uint4 u = *(const uint4*)(h2m + (size_t)(m & 0x1FFFF) * OUT_DIM + 8 * t);
            float2 f;
            f = unpack_half2(u.x); a[0] += vl * f.x; a[1] += vl * f.y;
            f = unpack_half2(u.y); a[2] += vl * f.x; a[3] += vl * f.y;
            f = unpack_half2(u.z); a[4] += vl * f.x; a[5] += vl * f.y;
            f = unpack_half2(u.w); a[6] += vl * f.x; a[7] += vl * f.y;
        }
        float s = dinv[(size_t)c * N_NODES + v];   // self-loop: s*h23s[v]
        uint4 u = *(const uint4*)(h2m + (size_t)v * OUT_DIM + 8 * t);
        float2 f0 = unpack_half2(u.x), f1 = unpack_half2(u.y);
        float2 f2 = unpack_half2(u.z), f3 = unpack_half2(u.w);
        a[0] += s * f0.x; a[1] += s * f0.y; a[2] += s * f1.x; a[3] += s * f1.y;
        a[4] += s * f2.x; a[5] += s * f2.y; a[6] += s * f3.x; a[7] += s * f3.y;
    }
    float4 o0, o1;
    o0.x = a[0]; o0.y = a[1]; o0.z = a[2]; o0.w = a[3];
    o1.x = a[4]; o1.y = a[5]; o1.z = a[6]; o1.w = a[7];
    *(float4*)(out + (size_t)v * OUT_DIM + t * 8) = o0;
    *(float4*)(out + (size_t)v * OUT_DIM + t * 8 + 4) = o1;
}

// ---------------- launch ----------------

extern "C" void kernel_launch(void* const* d_in, const int* in_sizes, int n_in,
                              void* d_out, int out_size, void* d_ws, size_t ws_size,
                              hipStream_t stream) {
    const float* x[3];  const int* ei[3];  const float* ea[3];
    const float* W[3];  const float* b[3]; const float* Wo[3]; const float* bo[3];
    for (int c = 0; c < 3; c++) {
        x[c]  = (const float*)d_in[7 * c + 0];
        ei[c] = (const int*)  d_in[7 * c + 1];
        ea[c] = (const float*)d_in[7 * c + 2];
        W[c]  = (const float*)d_in[7 * c + 3];
        b[c]  = (const float*)d_in[7 * c + 4];
        Wo[c] = (const float*)d_in[7 * c + 5];
        bo[c] = (const float*)d_in[7 * c + 6];
    }
    const float* att_w = (const float*)d_in[21];
    float* out = (float*)d_out;                 // [N*32] then 3x [N] weights
    float* wout = out + (size_t)N_NODES * OUT_DIM;

    // workspace layout (4-byte units) — total 92.0 MB (same as proven round-0 layout)
    int*   wsb      = (int*)d_ws;
    float* dinv     = (float*)wsb;                            // 3N
    int*   row_ptr  = wsb + 3 * N_NODES;                      // 3N+1 (+3 pad)
    int*   blocksum = row_ptr + 3 * N_NODES + 4;              // 512
    size_t stg_off  = (size_t)(3 * N_NODES + 3 * N_NODES + 4 + 512);
    stg_off = (stg_off + 3) & ~(size_t)3;                     // 16B align
    int2*  stg      = (int2*)(wsb + stg_off);                 // 3E int2 (38.4 MB)
    u32*   csr      = (u32*)(stg + 3 * (size_t)N_EDGES);      // 3E u32 (19.2 MB)
    u16*   hA       = (u16*)(csr + 3 * (size_t)N_EDGES);      // 3*N*32 fp16 (19.2 MB)
    // hist_t/rp1 alias hA: dead before matmul_in3 writes h3 (1.8 MB < 19.2 MB)
    int*   hist_t   = (int*)hA;                               // SC_N
    int*   rp1      = hist_t + SC_N;                          // SC_N+1
    float* hmix     = (float*)(hA + 3 * (size_t)N_NODES * HID_DIM); // N*32 fp32

    const int B = 256;

    // CSR build: hist -> scan(2 kernels) -> bin -> per-bucket row-sorted counting sort
    binhist_kernel<<<PB, BINB, 0, stream>>>(ei[0], ei[1], ei[2], hist_t);
    scan1_kernel<<<SC_G, B, 0, stream>>>(hist_t, rp1, blocksum);
    scan2_kernel<<<1, B, 0, stream>>>(blocksum, SC_G);
    binscatter_kernel<<<PB, BINB, 0, stream>>>(ei[0], ei[1], ei[2], ea[0], ea[1], ea[2],
                                               rp1, blocksum, stg);
    bucket_sort_kernel<<<NBT, B, 0, stream>>>(stg, rp1, blocksum, csr, dinv, row_ptr);

    // layer 1: 3-channel matmul (fdot2, fp16 W in LDS, 2-node blocking), fused gather
    matmul_in3_kernel<<<3 * MM2, B, 0, stream>>>(x[0], x[1], x[2], W[0], W[1], W[2],
                                                 dinv, hA);
    gather_combine_kernel<<<GN4, B, 0, stream>>>(row_ptr, csr, hA, dinv,
                                                 b[0], b[1], b[2], att_w, hmix, wout);

    // layer 2: 3-channel matmul (h3 dead -> h23 reuses hA), fused gather -> out
    matmul_hid3_kernel<<<3 * MM2, B, 0, stream>>>(hmix, Wo[0], Wo[1], Wo[2], dinv, hA);
    gather_out_kernel<<<GN4, B, 0, stream>>>(row_ptr, csr, hA, dinv,
                                             bo[0], bo[1], bo[2], out);
}

// Round 9
// 562.485 us; speedup vs baseline: 1.1213x; 1.1213x over previous
//
#include <hip/hip_runtime.h>
#include <hip/hip_fp16.h>

typedef unsigned short u16;
typedef unsigned int   u32;
typedef _Float16 h2 __attribute__((ext_vector_type(2)));

#define N_NODES 100000
#define N_EDGES 1600000
#define IN_DIM  128
#define HID_DIM 32
#define OUT_DIM 32

#define BK   512                 // cols per bucket (512 -> 32-entry/256B scatter runs)
#define NBC  196                 // buckets per channel = ceil(100000/512)
#define NBT  (3 * NBC)           // 588 total buckets

#define PB    256                // binning blocks = 1 per CU (3E = 256*18750 exactly)
#define BINB  1024               // binning block size (16 waves)
#define CHUNK 18750              // edges per binning block
#define SC_N  (NBT * PB)         // 150528 scan elements (multiple of 8)
#define SC_CHUNK 2048
#define SC_G  ((SC_N + SC_CHUNK - 1) / SC_CHUNK)   // 74
#define GN4  ((N_NODES * 4 + 255) / 256) // 1563 blocks for 4-threads-per-node kernels
#define MM2  ((N_NODES + 63) / 64)       // 1563 matmul blocks/channel (64 nodes/block)

#define KEYB 4                   // row-bucket bits: row>>13 in 0..12 (fits 4 bits)
#define NKEY (BK << KEYB)        // 8192 sort keys: (cl<<4) | (row>>13)

// final ofs value without materializing scan3: ofs(m) = m ? rp1[m] + bs[(m-1)>>11] : 0
__device__ inline int ofs_at(const int* __restrict__ rp1, const int* __restrict__ bs, int m) {
    return m ? rp1[m] + bs[(m - 1) >> 11] : 0;
}

// ---------------- phase 1: per-block bucket histogram ----------------

__global__ void binhist_kernel(const int* __restrict__ ei0, const int* __restrict__ ei1,
                               const int* __restrict__ ei2, int* __restrict__ hist_t) {
    __shared__ int hloc[NBT];
    for (int i = threadIdx.x; i < NBT; i += blockDim.x) hloc[i] = 0;
    __syncthreads();
    int b = blockIdx.x;
    int beg = b * CHUNK, end = beg + CHUNK;
    for (int e = beg + threadIdx.x; e < end; e += blockDim.x) {
        int c = (e >= 2 * N_EDGES) ? 2 : (e >= N_EDGES ? 1 : 0);
        const int* ei = (c == 0) ? ei0 : (c == 1) ? ei1 : ei2;
        int col = ei[N_EDGES + (e - c * N_EDGES)];
        atomicAdd(&hloc[c * NBC + (col >> 9)], 1);
    }
    __syncthreads();
    for (int g = threadIdx.x; g < NBT; g += blockDim.x)
        hist_t[g * PB + b] = hloc[g];
}

// ---------------- phase 2: 2-kernel scan over hist_t[SC_N] -> rp1 (+blocksum) ----

__global__ void scan1_kernel(const int* __restrict__ counts, int* __restrict__ rp1,
                             int* __restrict__ blocksum) {
    __shared__ int wsum[4];
    int tid = threadIdx.x;
    int base = blockIdx.x * SC_CHUNK + tid * 8;
    int vals[8];
    int tsum = 0;
    if (base < SC_N) {          // SC_N multiple of 8 -> all-or-nothing per thread
        int4 v0 = *(const int4*)(counts + base);
        int4 v1 = *(const int4*)(counts + base + 4);
        vals[0] = v0.x; vals[1] = v0.y; vals[2] = v0.z; vals[3] = v0.w;
        vals[4] = v1.x; vals[5] = v1.y; vals[6] = v1.z; vals[7] = v1.w;
#pragma unroll
        for (int k = 0; k < 8; k++) tsum += vals[k];
    } else {
#pragma unroll
        for (int k = 0; k < 8; k++) vals[k] = 0;
    }
    int lane = tid & 63, wave = tid >> 6;
    int x = tsum;
    for (int d = 1; d < 64; d <<= 1) {
        int t = __shfl_up(x, d, 64);
        if (lane >= d) x += t;
    }
    if (lane == 63) wsum[wave] = x;
    __syncthreads();
    int woff = 0;
    for (int w = 0; w < wave; w++) woff += wsum[w];
    int run = woff + x - tsum;
    if (base < SC_N) {
#pragma unroll
        for (int k = 0; k < 8; k++) {
            run += vals[k];
            rp1[base + k + 1] = run;
        }
    }
    if (tid == blockDim.x - 1) blocksum[blockIdx.x] = woff + x;
    if (blockIdx.x == 0 && tid == 0) rp1[0] = 0;
}

// single block, loops over n entries in chunks of 256 with carry
__global__ void scan2_kernel(int* __restrict__ blocksum, int n) {
    __shared__ int wsum[4];
    int tid = threadIdx.x;
    int lane = tid & 63, wave = tid >> 6;
    int carry = 0;
    for (int base = 0; base < n; base += 256) {
        int i = base + tid;
        int v = (i < n) ? blocksum[i] : 0;
        int x = v;
        for (int d = 1; d < 64; d <<= 1) {
            int t = __shfl_up(x, d, 64);
            if (lane >= d) x += t;
        }
        if (lane == 63) wsum[wave] = x;
        __syncthreads();
        int woff = 0;
        for (int w = 0; w < wave; w++) woff += wsum[w];
        int total = wsum[0] + wsum[1] + wsum[2] + wsum[3];
        if (i < n) blocksum[i] = carry + woff + x - v;   // exclusive
        carry += total;
        __syncthreads();
    }
}

// ---------------- phase 3: binning scatter (no global atomics) ----------------
// entry: x = row | (colLow<<17) (9-bit colLow), y = ea bits (fp32)

__global__ void binscatter_kernel(const int* __restrict__ ei0, const int* __restrict__ ei1,
                                  const int* __restrict__ ei2,
                                  const float* __restrict__ ea0, const float* __restrict__ ea1,
                                  const float* __restrict__ ea2,
                                  const int* __restrict__ rp1, const int* __restrict__ bsum,
                                  int2* __restrict__ stg) {
    __shared__ int base_l[NBT];
    int b = blockIdx.x;
    for (int g = threadIdx.x; g < NBT; g += blockDim.x)
        base_l[g] = ofs_at(rp1, bsum, g * PB + b);
    __syncthreads();
    int beg = b * CHUNK, end = beg + CHUNK;
    for (int e = beg + threadIdx.x; e < end; e += blockDim.x) {
        int c = (e >= 2 * N_EDGES) ? 2 : (e >= N_EDGES ? 1 : 0);
        int le = e - c * N_EDGES;
        const int* ei = (c == 0) ? ei0 : (c == 1) ? ei1 : ei2;
        const float* ea = (c == 0) ? ea0 : (c == 1) ? ea1 : ea2;
        int row = ei[le];
        int col = ei[N_EDGES + le];
        int g = c * NBC + (col >> 9);
        int slot = atomicAdd(&base_l[g], 1);   // LDS atomic, block-local
        stg[slot] = make_int2(row | ((col & 511) << 17), __float_as_int(ea[le]));
    }
}

// ---------------- phase 4: per-bucket counting sort -> packed CSR + dinv + row_ptr ----
// csr entry: row(17b) | fp16(ea*dinv[col]) sans sign bit (15b).
// Sort key = (cl<<4)|(row>>13): row-sorted within col -> gather L2-window locality.
// No LDS edge buffer (stg re-read in pass 2, L2/L3-hot) -> no capacity limit;
// hist doubles as cursor in pass 2 (atomicAdd returns slot).

__global__ void bucket_sort_kernel(const int2* __restrict__ stg, const int* __restrict__ rp1,
                                   const int* __restrict__ bsum,
                                   u32* __restrict__ csr,
                                   float* __restrict__ dinv, int* __restrict__ row_ptr) {
    __shared__ int hist[NKEY];         // 32 KB; prefix after scan, cursor in pass 2
    __shared__ int colStart[BK];       // 2 KB
    __shared__ float deg[BK];          // 2 KB
    __shared__ float dl[BK];           // 2 KB
    __shared__ int wsum[4];
    int tid = threadIdx.x;
    int g = blockIdx.x;
    int c = g / NBC;
    int colBase = (g % NBC) << 9;
    for (int i = tid; i < NKEY; i += 256) hist[i] = 0;
    deg[tid] = 1.0f;                   // self-loop
    deg[tid + 256] = 1.0f;
    __syncthreads();
    int beg = ofs_at(rp1, bsum, g * PB);
    int end = (g == NBT - 1) ? 3 * N_EDGES : ofs_at(rp1, bsum, (g + 1) * PB);
    int cnt = end - beg;
    // pass 1: count keys + accumulate deg
    for (int i = tid; i < cnt; i += blockDim.x) {
        int2 p = stg[beg + i];
        int cl = (p.x >> 17) & 511;
        int row = p.x & 0x1FFFF;
        atomicAdd(&hist[(cl << KEYB) | (row >> 13)], 1);
        atomicAdd(&deg[cl], __int_as_float(p.y));
    }
    __syncthreads();
    // exclusive scan of hist[8192] in place (32 entries = 2 cols per thread)
    int base32 = tid * 32;
    int v[32]; int tsum = 0;
#pragma unroll
    for (int k = 0; k < 32; k++) { v[k] = hist[base32 + k]; tsum += v[k]; }
    int lane = tid & 63, wave = tid >> 6;
    int xs = tsum;
    for (int d = 1; d < 64; d <<= 1) {
        int tt = __shfl_up(xs, d, 64);
        if (lane >= d) xs += tt;
    }
    if (lane == 63) wsum[wave] = xs;
    __syncthreads();
    int woff = 0;
    for (int w = 0; w < wave; w++) woff += wsum[w];
    int run = woff + xs - tsum;        // exclusive prefix of this thread's first key
#pragma unroll
    for (int k = 0; k < 32; k++) {
        if (k == 0)  colStart[2 * tid]     = run;   // start of col 2*tid
        if (k == 16) colStart[2 * tid + 1] = run;   // start of col 2*tid+1
        int t2 = v[k]; hist[base32 + k] = run; run += t2;
    }
    dl[tid] = rsqrtf(deg[tid]);        // deg >= 1
    dl[tid + 256] = rsqrtf(deg[tid + 256]);
    __syncthreads();                   // prefix + colStart + dl visible to all
    // pass 2: re-read stg (cache-hot), scatter to final csr slot via cursor
    for (int i = tid; i < cnt; i += blockDim.x) {
        int2 p = stg[beg + i];
        int cl = (p.x >> 17) & 511;
        int row = p.x & 0x1FFFF;
        int key = (cl << KEYB) | (row >> 13);
        int slot = atomicAdd(&hist[key], 1);
        float vv = __int_as_float(p.y) * dl[cl];  // in [0,1): fp16 sign bit = 0
        __half h = __float2half(vv);
        u32 hb = (u32)(*(u16*)&h) & 0x7FFF;
        csr[beg + slot] = (u32)row | (hb << 17);
    }
#pragma unroll
    for (int q = 0; q < 2; q++) {
        int cl = tid + q * 256;
        int col = colBase + cl;
        if (col < N_NODES) {
            dinv[(size_t)c * N_NODES + col] = dl[cl];
            row_ptr[(size_t)c * N_NODES + col] = beg + colStart[cl];
        }
    }
    if (g == NBT - 1 && tid == 0) row_ptr[3 * N_NODES] = 3 * N_EDGES;
}

// ---------------- fp16 helpers ----------------

__device__ inline u32 pack_half2(float a, float b) {
    __half2 h = __floats2half2_rn(a, b);
    union { __half2 h; u32 u; } cv; cv.h = h;
    return cv.u;
}

__device__ inline float2 unpack_half2(u32 u) {
    union { u32 u; __half2 h; } cv; cv.u = u;
    return __half22float2(cv.h);
}

__device__ inline float val15(u32 meta) {       // decode 15-bit fp16 payload
    return unpack_half2(meta >> 17).x;          // high half = 0, ignored
}

// v_dot2_f32_f16: a.x*b.x + a.y*b.y + c, fp32 accumulate (f16 products exact in f32)
__device__ inline float fdot2h(u32 a, u32 b, float c) {
    union { u32 u; h2 h; } ca, cb; ca.u = a; cb.u = b;
    return __builtin_amdgcn_fdot2(ca.h, cb.h, c, false);
}

// ---------------- matmul (3 channels): x_c[N,128] @ W_c[128,32], scale by dinv, fp16 ----

__global__ void matmul_in3_kernel(const float* __restrict__ x0, const float* __restrict__ x1,
                                  const float* __restrict__ x2,
                                  const float* __restrict__ W0, const float* __restrict__ W1,
                                  const float* __restrict__ W2,
                                  const float* __restrict__ dinv,
                                  u16* __restrict__ h3) {
    __shared__ u32 Ws2[(IN_DIM / 2) * HID_DIM];   // 8 KB: [jp][d] = half2(W[2jp][d],W[2jp+1][d])
    int c = blockIdx.x / MM2;
    int lb = blockIdx.x % MM2;
    const float* x = (c == 0) ? x0 : (c == 1) ? x1 : x2;
    const float* W = (c == 0) ? W0 : (c == 1) ? W1 : W2;
    for (int i = threadIdx.x; i < (IN_DIM / 2) * HID_DIM; i += blockDim.x) {
        int d = i & 31, jp = i >> 5;
        Ws2[i] = pack_half2(W[(2 * jp) * HID_DIM + d], W[(2 * jp + 1) * HID_DIM + d]);
    }
    __syncthreads();
    int t = threadIdx.x & 7;          // output dim slice 4t..4t+3
    int grp = threadIdx.x >> 3;       // 0..31
    int v0 = lb * 64 + grp * 2;       // 2 consecutive nodes
    if (v0 >= N_NODES) return;        // N_NODES even -> all-or-nothing per thread
    float a[2][4];
#pragma unroll
    for (int k = 0; k < 2; k++)
#pragma unroll
        for (int d = 0; d < 4; d++) a[k][d] = 0.f;
    const float* xr0 = x + (size_t)v0 * IN_DIM;
    const float* xr1 = xr0 + IN_DIM;
#pragma unroll 4
    for (int q = 0; q < 32; q++) {    // 4 K per iter (jp = 2q, 2q+1)
        float4 xv0 = *(const float4*)(xr0 + 4 * q);
        float4 xv1 = *(const float4*)(xr1 + 4 * q);
        u32 p00 = pack_half2(xv0.x, xv0.y), p01 = pack_half2(xv0.z, xv0.w);
        u32 p10 = pack_half2(xv1.x, xv1.y), p11 = pack_half2(xv1.z, xv1.w);
        uint4 wA = *(const uint4*)&Ws2[(2 * q) * HID_DIM + 4 * t];
        uint4 wB = *(const uint4*)&Ws2[(2 * q + 1) * HID_DIM + 4 * t];
        a[0][0] = fdot2h(p00, wA.x, a[0][0]); a[0][1] = fdot2h(p00, wA.y, a[0][1]);
        a[0][2] = fdot2h(p00, wA.z, a[0][2]); a[0][3] = fdot2h(p00, wA.w, a[0][3]);
        a[0][0] = fdot2h(p01, wB.x, a[0][0]); a[0][1] = fdot2h(p01, wB.y, a[0][1]);
        a[0][2] = fdot2h(p01, wB.z, a[0][2]); a[0][3] = fdot2h(p01, wB.w, a[0][3]);
        a[1][0] = fdot2h(p10, wA.x, a[1][0]); a[1][1] = fdot2h(p10, wA.y, a[1][1]);
        a[1][2] = fdot2h(p10, wA.z, a[1][2]); a[1][3] = fdot2h(p10, wA.w, a[1][3]);
        a[1][0] = fdot2h(p11, wB.x, a[1][0]); a[1][1] = fdot2h(p11, wB.y, a[1][1]);
        a[1][2] = fdot2h(p11, wB.z, a[1][2]); a[1][3] = fdot2h(p11, wB.w, a[1][3]);
    }
#pragma unroll
    for (int k = 0; k < 2; k++) {
        float s = dinv[(size_t)c * N_NODES + v0 + k];
        uint2 pk = make_uint2(pack_half2(a[k][0] * s, a[k][1] * s),
                              pack_half2(a[k][2] * s, a[k][3] * s));
        *(uint2*)(h3 + ((size_t)c * N_NODES + v0 + k) * HID_DIM + 4 * t) = pk;
    }
}

// ---------------- matmul (3 channels): hmix[N,32] @ Wo_c[32,32], scale by dinv, fp16 ----

__global__ void matmul_hid3_kernel(const float* __restrict__ hmix,
                                   const float* __restrict__ Wo0, const float* __restrict__ Wo1,
                                   const float* __restrict__ Wo2,
                                   const float* __restrict__ dinv,
                                   u16* __restrict__ h23) {
    __shared__ u32 Ws2[(HID_DIM / 2) * OUT_DIM];  // 2 KB
    int c = blockIdx.x / MM2;
    int lb = blockIdx.x % MM2;
    const float* Wo = (c == 0) ? Wo0 : (c == 1) ? Wo1 : Wo2;
    for (int i = threadIdx.x; i < (HID_DIM / 2) * OUT_DIM; i += blockDim.x) {
        int d = i & 31, jp = i >> 5;
        Ws2[i] = pack_half2(Wo[(2 * jp) * OUT_DIM + d], Wo[(2 * jp + 1) * OUT_DIM + d]);
    }
    __syncthreads();
    int t = threadIdx.x & 7;
    int grp = threadIdx.x >> 3;
    int v0 = lb * 64 + grp * 2;
    if (v0 >= N_NODES) return;
    float a[2][4];
#pragma unroll
    for (int k = 0; k < 2; k++)
#pragma unroll
        for (int d = 0; d < 4; d++) a[k][d] = 0.f;
    const float* hr0 = hmix + (size_t)v0 * HID_DIM;
    const float* hr1 = hr0 + HID_DIM;
#pragma unroll
    for (int q = 0; q < 8; q++) {
        float4 xv0 = *(const float4*)(hr0 + 4 * q);
        float4 xv1 = *(const float4*)(hr1 + 4 * q);
        u32 p00 = pack_half2(xv0.x, xv0.y), p01 = pack_half2(xv0.z, xv0.w);
        u32 p10 = pack_half2(xv1.x, xv1.y), p11 = pack_half2(xv1.z, xv1.w);
        uint4 wA = *(const uint4*)&Ws2[(2 * q) * OUT_DIM + 4 * t];
        uint4 wB = *(const uint4*)&Ws2[(2 * q + 1) * OUT_DIM + 4 * t];
        a[0][0] = fdot2h(p00, wA.x, a[0][0]); a[0][1] = fdot2h(p00, wA.y, a[0][1]);
        a[0][2] = fdot2h(p00, wA.z, a[0][2]); a[0][3] = fdot2h(p00, wA.w, a[0][3]);
        a[0][0] = fdot2h(p01, wB.x, a[0][0]); a[0][1] = fdot2h(p01, wB.y, a[0][1]);
        a[0][2] = fdot2h(p01, wB.z, a[0][2]); a[0][3] = fdot2h(p01, wB.w, a[0][3]);
        a[1][0] = fdot2h(p10, wA.x, a[1][0]); a[1][1] = fdot2h(p10, wA.y, a[1][1]);
        a[1][2] = fdot2h(p10, wA.z, a[1][2]); a[1][3] = fdot2h(p10, wA.w, a[1][3]);
        a[1][0] = fdot2h(p11, wB.x, a[1][0]); a[1][1] = fdot2h(p11, wB.y, a[1][1]);
        a[1][2] = fdot2h(p11, wB.z, a[1][2]); a[1][3] = fdot2h(p11, wB.w, a[1][3]);
    }
#pragma unroll
    for (int k = 0; k < 2; k++) {
        float s = dinv[(size_t)c * N_NODES + v0 + k];
        uint2 pk = make_uint2(pack_half2(a[k][0] * s, a[k][1] * s),
                              pack_half2(a[k][2] * s, a[k][3] * s));
        *(uint2*)(h23 + ((size_t)c * N_NODES + v0 + k) * OUT_DIM + 4 * t) = pk;
    }
}

// ---------------- fused layer-1 gather (3 channels) + attention combine ----------------
// 4 lanes/node, 8 dims/lane (uint4 = 16B row loads).  Edge loop unrolled x4.

__global__ void gather_combine_kernel(const int* __restrict__ row_ptr,
                                      const u32* __restrict__ csr,
                                      const u16* __restrict__ h3,
                                      const float* __restrict__ dinv,
                                      const float* __restrict__ b0,
                                      const float* __restrict__ b1,
                                      const float* __restrict__ b2,
                                      const float* __restrict__ att_w,
                                      float* __restrict__ hmix,
                                      float* __restrict__ wout) {
    int gid = blockIdx.x * blockDim.x + threadIdx.x;
    int v = gid >> 2;
    int t = gid & 3;
    if (v >= N_NODES) return;
    float4 wv0 = *(const float4*)(att_w + t * 8);
    float4 wv1 = *(const float4*)(att_w + t * 8 + 4);
    float e[3][8];
    float coef[3];
#pragma unroll
    for (int c = 0; c < 3; c++) {
        const u16* h = h3 + (size_t)c * N_NODES * HID_DIM;
        const float* bb = (c == 0) ? b0 : (c == 1) ? b1 : b2;
        int beg = row_ptr[c * N_NODES + v], end = row_ptr[c * N_NODES + v + 1];
        float a[8];
#pragma unroll
        for (int k = 0; k < 8; k++) a[k] = 0.f;
        int ee = beg;
        for (; ee + 4 <= end; ee += 4) {
            u32 m0 = csr[ee], m1 = csr[ee + 1], m2 = csr[ee + 2], m3 = csr[ee + 3];
            uint4 u0 = *(const uint4*)(h + (size_t)(m0 & 0x1FFFF) * HID_DIM + 8 * t);
            uint4 u1 = *(const uint4*)(h + (size_t)(m1 & 0x1FFFF) * HID_DIM + 8 * t);
            uint4 u2 = *(const uint4*)(h + (size_t)(m2 & 0x1FFFF) * HID_DIM + 8 * t);
            uint4 u3 = *(const uint4*)(h + (size_t)(m3 & 0x1FFFF) * HID_DIM + 8 * t);
            float vl0 = val15(m0), vl1 = val15(m1), vl2 = val15(m2), vl3 = val15(m3);
            float2 f;
            f = unpack_half2(u0.x); a[0] += vl0 * f.x; a[1] += vl0 * f.y;
            f = unpack_half2(u0.y); a[2] += vl0 * f.x; a[3] += vl0 * f.y;
            f = unpack_half2(u0.z); a[4] += vl0 * f.x; a[5] += vl0 * f.y;
            f = unpack_half2(u0.w); a[6] += vl0 * f.x; a[7] += vl0 * f.y;
            f = unpack_half2(u1.x); a[0] += vl1 * f.x; a[1] += vl1 * f.y;
            f = unpack_half2(u1.y); a[2] += vl1 * f.x; a[3] += vl1 * f.y;
            f = unpack_half2(u1.z); a[4] += vl1 * f.x; a[5] += vl1 * f.y;
            f = unpack_half2(u1.w); a[6] += vl1 * f.x; a[7] += vl1 * f.y;
            f = unpack_half2(u2.x); a[0] += vl2 * f.x; a[1] += vl2 * f.y;
            f = unpack_half2(u2.y); a[2] += vl2 * f.x; a[3] += vl2 * f.y;
            f = unpack_half2(u2.z); a[4] += vl2 * f.x; a[5] += vl2 * f.y;
            f = unpack_half2(u2.w); a[6] += vl2 * f.x; a[7] += vl2 * f.y;
            f = unpack_half2(u3.x); a[0] += vl3 * f.x; a[1] += vl3 * f.y;
            f = unpack_half2(u3.y); a[2] += vl3 * f.x; a[3] += vl3 * f.y;
            f = unpack_half2(u3.z); a[4] += vl3 * f.x; a[5] += vl3 * f.y;
            f = unpack_half2(u3.w); a[6] += vl3 * f.x; a[7] += vl3 * f.y;
        }
        for (; ee < end; ee++) {
            u32 m = csr[ee];
            float vl = val15(m);
            uint4 u = *(const uint4*)(h + (size_t)(m & 0x1FFFF) * HID_DIM + 8 * t);
            float2 f;
            f = unpack_half2(u.x); a[0] += vl * f.x; a[1] += vl * f.y;
            f = unpack_half2(u.y); a[2] += vl * f.x; a[3] += vl * f.y;
            f = unpack_half2(u.z); a[4] += vl * f.x; a[5] += vl * f.y;
            f = unpack_half2(u.w); a[6] += vl * f.x; a[7] += vl * f.y;
        }
        float s = dinv[(size_t)c * N_NODES + v];   // self-loop: s^2*h[v] = s*h3s[v]
        uint4 u = *(const uint4*)(h + (size_t)v * HID_DIM + 8 * t);
        float2 f0 = unpack_half2(u.x), f1 = unpack_half2(u.y);
        float2 f2 = unpack_half2(u.z), f3 = unpack_half2(u.w);
        float4 bv0 = *(const float4*)(bb + t * 8);
        float4 bv1 = *(const float4*)(bb + t * 8 + 4);
        e[c][0] = fmaxf(a[0] + s * f0.x + bv0.x, 0.f);
        e[c][1] = fmaxf(a[1] + s * f0.y + bv0.y, 0.f);
        e[c][2] = fmaxf(a[2] + s * f1.x + bv0.z, 0.f);
        e[c][3] = fmaxf(a[3] + s * f1.y + bv0.w, 0.f);
        e[c][4] = fmaxf(a[4] + s * f2.x + bv1.x, 0.f);
        e[c][5] = fmaxf(a[5] + s * f2.y + bv1.y, 0.f);
        e[c][6] = fmaxf(a[6] + s * f3.x + bv1.z, 0.f);
        e[c][7] = fmaxf(a[7] + s * f3.y + bv1.w, 0.f);
        float dot = e[c][0] * wv0.x + e[c][1] * wv0.y + e[c][2] * wv0.z + e[c][3] * wv0.w
                  + e[c][4] * wv1.x + e[c][5] * wv1.y + e[c][6] * wv1.z + e[c][7] * wv1.w;
        dot += __shfl_xor(dot, 1, 64);
        dot += __shfl_xor(dot, 2, 64);   // all 4 lanes of the group hold the full dot
        float lr = (dot > 0.0f) ? dot : 0.01f * dot;
        coef[c] = expf(lr);
    }
    float inv = 1.0f / (coef[0] + coef[1] + coef[2]);
    float w0 = coef[0] * inv, w1 = coef[1] * inv, w2 = coef[2] * inv;
    if (t == 0) {
        wout[v] = w0;
        wout[N_NODES + v] = w1;
        wout[2 * N_NODES + v] = w2;
    }
    float4 r0, r1;
    r0.x = w0 * e[0][0] + w1 * e[1][0] + w2 * e[2][0];
    r0.y = w0 * e[0][1] + w1 * e[1][1] + w2 * e[2][1];
    r0.z = w0 * e[0][2] + w1 * e[1][2] + w2 * e[2][2];
    r0.w = w0 * e[0][3] + w1 * e[1][3] + w2 * e[2][3];
    r1.x = w0 * e[0][4] + w1 * e[1][4] + w2 * e[2][4];
    r1.y = w0 * e[0][5] + w1 * e[1][5] + w2 * e[2][5];
    r1.z = w0 * e[0][6] + w1 * e[1][6] + w2 * e[2][6];
    r1.w = w0 * e[0][7] + w1 * e[1][7] + w2 * e[2][7];
    *(float4*)(hmix + (size_t)v * HID_DIM + t * 8) = r0;
    *(float4*)(hmix + (size_t)v * HID_DIM + t * 8 + 4) = r1;
}

// ---------------- fused layer-2 gather (3 channels) + self-loops + biases -> out ----

__global__ void gather_out_kernel(const int* __restrict__ row_ptr,
                                  const u32* __restrict__ csr,
                                  const u16* __restrict__ h23,
                                  const float* __restrict__ dinv,
                                  const float* __restrict__ bo0,
                                  const float* __restrict__ bo1,
                                  const float* __restrict__ bo2,
                                  float* __restrict__ out) {
    int gid = blockIdx.x * blockDim.x + threadIdx.x;
    int v = gid >> 2;
    int t = gid & 3;
    if (v >= N_NODES) return;
    float4 p0 = *(const float4*)(bo0 + t * 8);
    float4 p1 = *(const float4*)(bo0 + t * 8 + 4);
    float4 q0 = *(const float4*)(bo1 + t * 8);
    float4 q1 = *(const float4*)(bo1 + t * 8 + 4);
    float4 s0 = *(const float4*)(bo2 + t * 8);
    float4 s1 = *(const float4*)(bo2 + t * 8 + 4);
    float a[8];
    a[0] = p0.x + q0.x + s0.x; a[1] = p0.y + q0.y + s0.y;
    a[2] = p0.z + q0.z + s0.z; a[3] = p0.w + q0.w + s0.w;
    a[4] = p1.x + q1.x + s1.x; a[5] = p1.y + q1.y + s1.y;
    a[6] = p1.z + q1.z + s1.z; a[7] = p1.w + q1.w + s1.w;
#pragma unroll
    for (int c = 0; c < 3; c++) {
        const u16* h2m = h23 + (size_t)c * N_NODES * OUT_DIM;
        int beg = row_ptr[c * N_NODES + v], end = row_ptr[c * N_NODES + v + 1];
        int ee = beg;
        for (; ee + 4 <= end; ee += 4) {
            u32 m0 = csr[ee], m1 = csr[ee + 1], m2 = csr[ee + 2], m3 = csr[ee + 3];
            uint4 u0 = *(const uint4*)(h2m + (size_t)(m0 & 0x1FFFF) * OUT_DIM + 8 * t);
            uint4 u1 = *(const uint4*)(h2m + (size_t)(m1 & 0x1FFFF) * OUT_DIM + 8 * t);
            uint4 u2 = *(const uint4*)(h2m + (size_t)(m2 & 0x1FFFF) * OUT_DIM + 8 * t);
            uint4 u3 = *(const uint4*)(h2m + (size_t)(m3 & 0x1FFFF) * OUT_DIM + 8 * t);
            float vl0 = val15(m0), vl1 = val15(m1), vl2 = val15(m2), vl3 = val15(m3);
            float2 f;
            f = unpack_half2(u0.x); a[0] += vl0 * f.x; a[1] += vl0 * f.y;
            f = unpack_half2(u0.y); a[2] += vl0 * f.x; a[3] += vl0 * f.y;
            f = unpack_half2(u0.z); a[4] += vl0 * f.x; a[5] += vl0 * f.y;
            f = unpack_half2(u0.w); a[6] += vl0 * f.x; a[7] += vl0 * f.y;
            f = unpack_half2(u1.x); a[0] += vl1 * f.x; a[1] += vl1 * f.y;
            f = unpack_half2(u1.y); a[2] += vl1 * f.x; a[3] += vl1 * f.y;
            f = unpack_half2(u1.z); a[4] += vl1 * f.x; a[5] += vl1 * f.y;
            f = unpack_half2(u1.w); a[6] += vl1 * f.x; a[7] += vl1 * f.y;
            f = unpack_half2(u2.x); a[0] += vl2 * f.x; a[1] += vl2 * f.y;
            f = unpack_half2(u2.y); a[2] += vl2 * f.x; a[3] += vl2 * f.y;
            f = unpack_half2(u2.z); a[4] += vl2 * f.x; a[5] += vl2 * f.y;
            f = unpack_half2(u2.w); a[6] += vl2 * f.x; a[7] += vl2 * f.y;
            f = unpack_half2(u3.x); a[0] += vl3 * f.x; a[1] += vl3 * f.y;
            f = unpack_half2(u3.y); a[2] += vl3 * f.x; a[3] += vl3 * f.y;
            f = unpack_half2(u3.z); a[4] += vl3 * f.x; a[5] += vl3 * f.y;
            f = unpack_half2(u3.w); a[6] += vl3 * f.x; a[7] += vl3 * f.y;
        }
        for (; ee < end; ee++) {
            u32 m = csr[ee];
            float vl = val15(m);
            uint4 u = *(const uint4*)(h2m + (size_t)(m & 0x1FFFF) * OUT_DIM + 8 * t);
            float2 f;
            f = unpack_half2(u.x); a[0] += vl * f.x; a[1] += vl * f.y;
            f = unpack_half2(u.y); a[2] += vl * f.x; a[3] += vl * f.y;
            f = unpack_half2(u.z); a[4] += vl * f.x; a[5] += vl * f.y;
            f = unpack_half2(u.w); a[6] += vl * f.x; a[7] += vl * f.y;
        }
        float s = dinv[(size_t)c * N_NODES + v];   // self-loop: s*h23s[v]
        uint4 u = *(const uint4*)(h2m + (size_t)v * OUT_DIM + 8 * t);
        float2 f0 = unpack_half2(u.x), f1 = unpack_half2(u.y);
        float2 f2 = unpack_half2(u.z), f3 = unpack_half2(u.w);
        a[0] += s * f0.x; a[1] += s * f0.y; a[2] += s * f1.x; a[3] += s * f1.y;
        a[4] += s * f2.x; a[5] += s * f2.y; a[6] += s * f3.x; a[7] += s * f3.y;
    }
    float4 o0, o1;
    o0.x = a[0]; o0.y = a[1]; o0.z = a[2]; o0.w = a[3];
    o1.x = a[4]; o1.y = a[5]; o1.z = a[6]; o1.w = a[7];
    *(float4*)(out + (size_t)v * OUT_DIM + t * 8) = o0;
    *(float4*)(out + (size_t)v * OUT_DIM + t * 8 + 4) = o1;
}

// ---------------- launch ----------------

extern "C" void kernel_launch(void* const* d_in, const int* in_sizes, int n_in,
                              void* d_out, int out_size, void* d_ws, size_t ws_size,
                              hipStream_t stream) {
    const float* x[3];  const int* ei[3];  const float* ea[3];
    const float* W[3];  const float* b[3]; const float* Wo[3]; const float* bo[3];
    for (int c = 0; c < 3; c++) {
        x[c]  = (const float*)d_in[7 * c + 0];
        ei[c] = (const int*)  d_in[7 * c + 1];
        ea[c] = (const float*)d_in[7 * c + 2];
        W[c]  = (const float*)d_in[7 * c + 3];
        b[c]  = (const float*)d_in[7 * c + 4];
        Wo[c] = (const float*)d_in[7 * c + 5];
        bo[c] = (const float*)d_in[7 * c + 6];
    }
    const float* att_w = (const float*)d_in[21];
    float* out = (float*)d_out;                 // [N*32] then 3x [N] weights
    float* wout = out + (size_t)N_NODES * OUT_DIM;

    // workspace layout (4-byte units) — total 92.0 MB (same as proven round-0 layout)
    int*   wsb      = (int*)d_ws;
    float* dinv     = (float*)wsb;                            // 3N
    int*   row_ptr  = wsb + 3 * N_NODES;                      // 3N+1 (+3 pad)
    int*   blocksum = row_ptr + 3 * N_NODES + 4;              // 512
    size_t stg_off  = (size_t)(3 * N_NODES + 3 * N_NODES + 4 + 512);
    stg_off = (stg_off + 3) & ~(size_t)3;                     // 16B align
    int2*  stg      = (int2*)(wsb + stg_off);                 // 3E int2 (38.4 MB)
    u32*   csr      = (u32*)(stg + 3 * (size_t)N_EDGES);      // 3E u32 (19.2 MB)
    u16*   hA       = (u16*)(csr + 3 * (size_t)N_EDGES);      // 3*N*32 fp16 (19.2 MB)
    // hist_t/rp1 alias hA: dead before matmul_in3 writes h3 (1.3 MB < 19.2 MB)
    int*   hist_t   = (int*)hA;                               // SC_N
    int*   rp1      = hist_t + SC_N;                          // SC_N+1
    float* hmix     = (float*)(hA + 3 * (size_t)N_NODES * HID_DIM); // N*32 fp32

    const int B = 256;

    // CSR build: hist -> scan(2 kernels) -> bin -> per-bucket row-sorted counting sort
    binhist_kernel<<<PB, BINB, 0, stream>>>(ei[0], ei[1], ei[2], hist_t);
    scan1_kernel<<<SC_G, B, 0, stream>>>(hist_t, rp1, blocksum);
    scan2_kernel<<<1, B, 0, stream>>>(blocksum, SC_G);
    binscatter_kernel<<<PB, BINB, 0, stream>>>(ei[0], ei[1], ei[2], ea[0], ea[1], ea[2],
                                               rp1, blocksum, stg);
    bucket_sort_kernel<<<NBT, B, 0, stream>>>(stg, rp1, blocksum, csr, dinv, row_ptr);

    // layer 1: 3-channel matmul (fdot2, fp16 W in LDS, 2-node blocking), fused gather
    matmul_in3_kernel<<<3 * MM2, B, 0, stream>>>(x[0], x[1], x[2], W[0], W[1], W[2],
                                                 dinv, hA);
    gather_combine_kernel<<<GN4, B, 0, stream>>>(row_ptr, csr, hA, dinv,
                                                 b[0], b[1], b[2], att_w, hmix, wout);

    // layer 2: 3-channel matmul (h3 dead -> h23 reuses hA), fused gather -> out
    matmul_hid3_kernel<<<3 * MM2, B, 0, stream>>>(hmix, Wo[0], Wo[1], Wo[2], dinv, hA);
    gather_out_kernel<<<GN4, B, 0, stream>>>(row_ptr, csr, hA, dinv,
                                             bo[0], bo[1], bo[2], out);
}

// Round 10
// 560.374 us; speedup vs baseline: 1.1255x; 1.0038x over previous
//
#include <hip/hip_runtime.h>
#include <hip/hip_fp16.h>

typedef unsigned short u16;
typedef unsigned int   u32;
typedef _Float16 h2 __attribute__((ext_vector_type(2)));

#define N_NODES 100000
#define N_EDGES 1600000
#define IN_DIM  128
#define HID_DIM 32
#define OUT_DIM 32

#define BK   512                 // cols per bucket (512 -> 256B scatter runs)
#define NBC  196                 // buckets per channel = ceil(100000/512)
#define NBT  (3 * NBC)           // 588 total buckets

#define PB    256                // binning blocks = 1 per CU (3E = 256*18750 exactly)
#define BINB  1024               // binning block size (16 waves)
#define CHUNK 18750              // edges per binning block
#define SC_N  (NBT * PB)         // 150528 scan elements (multiple of 8)
#define SC_CHUNK 2048
#define SC_G  ((SC_N + SC_CHUNK - 1) / SC_CHUNK)   // 74
#define GN4  ((N_NODES * 4 + 255) / 256) // 1563 blocks for 4-threads-per-node kernels
#define MM2  ((N_NODES + 63) / 64)       // 1563 matmul blocks/channel (64 nodes/block)

#define KEYB 4                   // row-bucket bits: row>>13 in 0..12 (fits 4 bits)
#define NKEY (BK << KEYB)        // 8192 sort keys: (cl<<4) | (row>>13)

// final ofs value without materializing scan3: ofs(m) = m ? rp1[m] + bs[(m-1)>>11] : 0
__device__ inline int ofs_at(const int* __restrict__ rp1, const int* __restrict__ bs, int m) {
    return m ? rp1[m] + bs[(m - 1) >> 11] : 0;
}

// ---------------- phase 1: per-block bucket histogram ----------------

__global__ void binhist_kernel(const int* __restrict__ ei0, const int* __restrict__ ei1,
                               const int* __restrict__ ei2, int* __restrict__ hist_t) {
    __shared__ int hloc[NBT];
    for (int i = threadIdx.x; i < NBT; i += blockDim.x) hloc[i] = 0;
    __syncthreads();
    int b = blockIdx.x;
    int beg = b * CHUNK, end = beg + CHUNK;
    for (int e = beg + threadIdx.x; e < end; e += blockDim.x) {
        int c = (e >= 2 * N_EDGES) ? 2 : (e >= N_EDGES ? 1 : 0);
        const int* ei = (c == 0) ? ei0 : (c == 1) ? ei1 : ei2;
        int col = ei[N_EDGES + (e - c * N_EDGES)];
        atomicAdd(&hloc[c * NBC + (col >> 9)], 1);
    }
    __syncthreads();
    for (int g = threadIdx.x; g < NBT; g += blockDim.x)
        hist_t[g * PB + b] = hloc[g];
}

// ---------------- phase 2: 2-kernel scan over hist_t[SC_N] -> rp1 (+blocksum) ----

__global__ void scan1_kernel(const int* __restrict__ counts, int* __restrict__ rp1,
                             int* __restrict__ blocksum) {
    __shared__ int wsum[4];
    int tid = threadIdx.x;
    int base = blockIdx.x * SC_CHUNK + tid * 8;
    int vals[8];
    int tsum = 0;
    if (base < SC_N) {          // SC_N multiple of 8 -> all-or-nothing per thread
        int4 v0 = *(const int4*)(counts + base);
        int4 v1 = *(const int4*)(counts + base + 4);
        vals[0] = v0.x; vals[1] = v0.y; vals[2] = v0.z; vals[3] = v0.w;
        vals[4] = v1.x; vals[5] = v1.y; vals[6] = v1.z; vals[7] = v1.w;
#pragma unroll
        for (int k = 0; k < 8; k++) tsum += vals[k];
    } else {
#pragma unroll
        for (int k = 0; k < 8; k++) vals[k] = 0;
    }
    int lane = tid & 63, wave = tid >> 6;
    int x = tsum;
    for (int d = 1; d < 64; d <<= 1) {
        int t = __shfl_up(x, d, 64);
        if (lane >= d) x += t;
    }
    if (lane == 63) wsum[wave] = x;
    __syncthreads();
    int woff = 0;
    for (int w = 0; w < wave; w++) woff += wsum[w];
    int run = woff + x - tsum;
    if (base < SC_N) {
#pragma unroll
        for (int k = 0; k < 8; k++) {
            run += vals[k];
            rp1[base + k + 1] = run;
        }
    }
    if (tid == blockDim.x - 1) blocksum[blockIdx.x] = woff + x;
    if (blockIdx.x == 0 && tid == 0) rp1[0] = 0;
}

// single block, loops over n entries in chunks of 256 with carry
__global__ void scan2_kernel(int* __restrict__ blocksum, int n) {
    __shared__ int wsum[4];
    int tid = threadIdx.x;
    int lane = tid & 63, wave = tid >> 6;
    int carry = 0;
    for (int base = 0; base < n; base += 256) {
        int i = base + tid;
        int v = (i < n) ? blocksum[i] : 0;
        int x = v;
        for (int d = 1; d < 64; d <<= 1) {
            int t = __shfl_up(x, d, 64);
            if (lane >= d) x += t;
        }
        if (lane == 63) wsum[wave] = x;
        __syncthreads();
        int woff = 0;
        for (int w = 0; w < wave; w++) woff += wsum[w];
        int total = wsum[0] + wsum[1] + wsum[2] + wsum[3];
        if (i < n) blocksum[i] = carry + woff + x - v;   // exclusive
        carry += total;
        __syncthreads();
    }
}

// ---------------- phase 3: binning scatter (no global atomics) ----------------
// entry: x = row | (colLow<<17) (9-bit colLow), y = ea bits (fp32)

__global__ void binscatter_kernel(const int* __restrict__ ei0, const int* __restrict__ ei1,
                                  const int* __restrict__ ei2,
                                  const float* __restrict__ ea0, const float* __restrict__ ea1,
                                  const float* __restrict__ ea2,
                                  const int* __restrict__ rp1, const int* __restrict__ bsum,
                                  int2* __restrict__ stg) {
    __shared__ int base_l[NBT];
    int b = blockIdx.x;
    for (int g = threadIdx.x; g < NBT; g += blockDim.x)
        base_l[g] = ofs_at(rp1, bsum, g * PB + b);
    __syncthreads();
    int beg = b * CHUNK, end = beg + CHUNK;
    for (int e = beg + threadIdx.x; e < end; e += blockDim.x) {
        int c = (e >= 2 * N_EDGES) ? 2 : (e >= N_EDGES ? 1 : 0);
        int le = e - c * N_EDGES;
        const int* ei = (c == 0) ? ei0 : (c == 1) ? ei1 : ei2;
        const float* ea = (c == 0) ? ea0 : (c == 1) ? ea1 : ea2;
        int row = ei[le];
        int col = ei[N_EDGES + le];
        int g = c * NBC + (col >> 9);
        int slot = atomicAdd(&base_l[g], 1);   // LDS atomic, block-local
        stg[slot] = make_int2(row | ((col & 511) << 17), __float_as_int(ea[le]));
    }
}

// ---------------- phase 4: per-bucket counting sort -> packed CSR + dinv + row_ptr ----
// csr entry: row(17b) | fp16(ea*dinv[col]) sans sign bit (15b).
// Sort key = (cl<<4)|(row>>13): row-sorted within col -> gather L2-window locality.

__global__ void bucket_sort_kernel(const int2* __restrict__ stg, const int* __restrict__ rp1,
                                   const int* __restrict__ bsum,
                                   u32* __restrict__ csr,
                                   float* __restrict__ dinv, int* __restrict__ row_ptr) {
    __shared__ int hist[NKEY];         // 32 KB; prefix after scan, cursor in pass 2
    __shared__ int colStart[BK];       // 2 KB
    __shared__ float deg[BK];          // 2 KB
    __shared__ float dl[BK];           // 2 KB
    __shared__ int wsum[4];
    int tid = threadIdx.x;
    int g = blockIdx.x;
    int c = g / NBC;
    int colBase = (g % NBC) << 9;
    for (int i = tid; i < NKEY; i += 256) hist[i] = 0;
    deg[tid] = 1.0f;                   // self-loop
    deg[tid + 256] = 1.0f;
    __syncthreads();
    int beg = ofs_at(rp1, bsum, g * PB);
    int end = (g == NBT - 1) ? 3 * N_EDGES : ofs_at(rp1, bsum, (g + 1) * PB);
    int cnt = end - beg;
    // pass 1: count keys + accumulate deg
    for (int i = tid; i < cnt; i += blockDim.x) {
        int2 p = stg[beg + i];
        int cl = (p.x >> 17) & 511;
        int row = p.x & 0x1FFFF;
        atomicAdd(&hist[(cl << KEYB) | (row >> 13)], 1);
        atomicAdd(&deg[cl], __int_as_float(p.y));
    }
    __syncthreads();
    // exclusive scan of hist[8192] in place (32 entries = 2 cols per thread)
    int base32 = tid * 32;
    int v[32]; int tsum = 0;
#pragma unroll
    for (int k = 0; k < 32; k++) { v[k] = hist[base32 + k]; tsum += v[k]; }
    int lane = tid & 63, wave = tid >> 6;
    int xs = tsum;
    for (int d = 1; d < 64; d <<= 1) {
        int tt = __shfl_up(xs, d, 64);
        if (lane >= d) xs += tt;
    }
    if (lane == 63) wsum[wave] = xs;
    __syncthreads();
    int woff = 0;
    for (int w = 0; w < wave; w++) woff += wsum[w];
    int run = woff + xs - tsum;        // exclusive prefix of this thread's first key
#pragma unroll
    for (int k = 0; k < 32; k++) {
        if (k == 0)  colStart[2 * tid]     = run;   // start of col 2*tid
        if (k == 16) colStart[2 * tid + 1] = run;   // start of col 2*tid+1
        int t2 = v[k]; hist[base32 + k] = run; run += t2;
    }
    dl[tid] = rsqrtf(deg[tid]);        // deg >= 1
    dl[tid + 256] = rsqrtf(deg[tid + 256]);
    __syncthreads();                   // prefix + colStart + dl visible to all
    // pass 2: re-read stg (cache-hot), scatter to final csr slot via cursor
    for (int i = tid; i < cnt; i += blockDim.x) {
        int2 p = stg[beg + i];
        int cl = (p.x >> 17) & 511;
        int row = p.x & 0x1FFFF;
        int key = (cl << KEYB) | (row >> 13);
        int slot = atomicAdd(&hist[key], 1);
        float vv = __int_as_float(p.y) * dl[cl];  // in [0,1): fp16 sign bit = 0
        __half h = __float2half(vv);
        u32 hb = (u32)(*(u16*)&h) & 0x7FFF;
        csr[beg + slot] = (u32)row | (hb << 17);
    }
#pragma unroll
    for (int q = 0; q < 2; q++) {
        int cl = tid + q * 256;
        int col = colBase + cl;
        if (col < N_NODES) {
            dinv[(size_t)c * N_NODES + col] = dl[cl];
            row_ptr[(size_t)c * N_NODES + col] = beg + colStart[cl];
        }
    }
    if (g == NBT - 1 && tid == 0) row_ptr[3 * N_NODES] = 3 * N_EDGES;
}

// ---------------- fp16 helpers ----------------

__device__ inline u32 pack_half2(float a, float b) {
    __half2 h = __floats2half2_rn(a, b);
    union { __half2 h; u32 u; } cv; cv.h = h;
    return cv.u;
}

__device__ inline float2 unpack_half2(u32 u) {
    union { u32 u; __half2 h; } cv; cv.u = u;
    return __half22float2(cv.h);
}

__device__ inline float val15(u32 meta) {       // decode 15-bit fp16 payload
    return unpack_half2(meta >> 17).x;          // high half = 0, ignored
}

// v_dot2_f32_f16: a.x*b.x + a.y*b.y + c, fp32 accumulate (f16 products exact in f32)
__device__ inline float fdot2h(u32 a, u32 b, float c) {
    union { u32 u; h2 h; } ca, cb; ca.u = a; cb.u = b;
    return __builtin_amdgcn_fdot2(ca.h, cb.h, c, false);
}

// ---------------- matmul (3 channels): x_c[N,128] @ W_c[128,32], scale by dinv, fp16 ----

__global__ void matmul_in3_kernel(const float* __restrict__ x0, const float* __restrict__ x1,
                                  const float* __restrict__ x2,
                                  const float* __restrict__ W0, const float* __restrict__ W1,
                                  const float* __restrict__ W2,
                                  const float* __restrict__ dinv,
                                  u16* __restrict__ h3) {
    __shared__ u32 Ws2[(IN_DIM / 2) * HID_DIM];   // 8 KB: [jp][d] = half2(W[2jp][d],W[2jp+1][d])
    int c = blockIdx.x / MM2;
    int lb = blockIdx.x % MM2;
    const float* x = (c == 0) ? x0 : (c == 1) ? x1 : x2;
    const float* W = (c == 0) ? W0 : (c == 1) ? W1 : W2;
    for (int i = threadIdx.x; i < (IN_DIM / 2) * HID_DIM; i += blockDim.x) {
        int d = i & 31, jp = i >> 5;
        Ws2[i] = pack_half2(W[(2 * jp) * HID_DIM + d], W[(2 * jp + 1) * HID_DIM + d]);
    }
    __syncthreads();
    int t = threadIdx.x & 7;          // output dim slice 4t..4t+3
    int grp = threadIdx.x >> 3;       // 0..31
    int v0 = lb * 64 + grp * 2;       // 2 consecutive nodes
    if (v0 >= N_NODES) return;        // N_NODES even -> all-or-nothing per thread
    float a[2][4];
#pragma unroll
    for (int k = 0; k < 2; k++)
#pragma unroll
        for (int d = 0; d < 4; d++) a[k][d] = 0.f;
    const float* xr0 = x + (size_t)v0 * IN_DIM;
    const float* xr1 = xr0 + IN_DIM;
#pragma unroll 4
    for (int q = 0; q < 32; q++) {    // 4 K per iter (jp = 2q, 2q+1)
        float4 xv0 = *(const float4*)(xr0 + 4 * q);
        float4 xv1 = *(const float4*)(xr1 + 4 * q);
        u32 p00 = pack_half2(xv0.x, xv0.y), p01 = pack_half2(xv0.z, xv0.w);
        u32 p10 = pack_half2(xv1.x, xv1.y), p11 = pack_half2(xv1.z, xv1.w);
        uint4 wA = *(const uint4*)&Ws2[(2 * q) * HID_DIM + 4 * t];
        uint4 wB = *(const uint4*)&Ws2[(2 * q + 1) * HID_DIM + 4 * t];
        a[0][0] = fdot2h(p00, wA.x, a[0][0]); a[0][1] = fdot2h(p00, wA.y, a[0][1]);
        a[0][2] = fdot2h(p00, wA.z, a[0][2]); a[0][3] = fdot2h(p00, wA.w, a[0][3]);
        a[0][0] = fdot2h(p01, wB.x, a[0][0]); a[0][1] = fdot2h(p01, wB.y, a[0][1]);
        a[0][2] = fdot2h(p01, wB.z, a[0][2]); a[0][3] = fdot2h(p01, wB.w, a[0][3]);
        a[1][0] = fdot2h(p10, wA.x, a[1][0]); a[1][1] = fdot2h(p10, wA.y, a[1][1]);
        a[1][2] = fdot2h(p10, wA.z, a[1][2]); a[1][3] = fdot2h(p10, wA.w, a[1][3]);
        a[1][0] = fdot2h(p11, wB.x, a[1][0]); a[1][1] = fdot2h(p11, wB.y, a[1][1]);
        a[1][2] = fdot2h(p11, wB.z, a[1][2]); a[1][3] = fdot2h(p11, wB.w, a[1][3]);
    }
#pragma unroll
    for (int k = 0; k < 2; k++) {
        float s = dinv[(size_t)c * N_NODES + v0 + k];
        uint2 pk = make_uint2(pack_half2(a[k][0] * s, a[k][1] * s),
                              pack_half2(a[k][2] * s, a[k][3] * s));
        *(uint2*)(h3 + ((size_t)c * N_NODES + v0 + k) * HID_DIM + 4 * t) = pk;
    }
}

// ---------------- matmul (3 channels): hmix[N,32] @ Wo_c[32,32], scale by dinv, fp16 ----

__global__ void matmul_hid3_kernel(const float* __restrict__ hmix,
                                   const float* __restrict__ Wo0, const float* __restrict__ Wo1,
                                   const float* __restrict__ Wo2,
                                   const float* __restrict__ dinv,
                                   u16* __restrict__ h23) {
    __shared__ u32 Ws2[(HID_DIM / 2) * OUT_DIM];  // 2 KB
    int c = blockIdx.x / MM2;
    int lb = blockIdx.x % MM2;
    const float* Wo = (c == 0) ? Wo0 : (c == 1) ? Wo1 : Wo2;
    for (int i = threadIdx.x; i < (HID_DIM / 2) * OUT_DIM; i += blockDim.x) {
        int d = i & 31, jp = i >> 5;
        Ws2[i] = pack_half2(Wo[(2 * jp) * OUT_DIM + d], Wo[(2 * jp + 1) * OUT_DIM + d]);
    }
    __syncthreads();
    int t = threadIdx.x & 7;
    int grp = threadIdx.x >> 3;
    int v0 = lb * 64 + grp * 2;
    if (v0 >= N_NODES) return;
    float a[2][4];
#pragma unroll
    for (int k = 0; k < 2; k++)
#pragma unroll
        for (int d = 0; d < 4; d++) a[k][d] = 0.f;
    const float* hr0 = hmix + (size_t)v0 * HID_DIM;
    const float* hr1 = hr0 + HID_DIM;
#pragma unroll
    for (int q = 0; q < 8; q++) {
        float4 xv0 = *(const float4*)(hr0 + 4 * q);
        float4 xv1 = *(const float4*)(hr1 + 4 * q);
        u32 p00 = pack_half2(xv0.x, xv0.y), p01 = pack_half2(xv0.z, xv0.w);
        u32 p10 = pack_half2(xv1.x, xv1.y), p11 = pack_half2(xv1.z, xv1.w);
        uint4 wA = *(const uint4*)&Ws2[(2 * q) * OUT_DIM + 4 * t];
        uint4 wB = *(const uint4*)&Ws2[(2 * q + 1) * OUT_DIM + 4 * t];
        a[0][0] = fdot2h(p00, wA.x, a[0][0]); a[0][1] = fdot2h(p00, wA.y, a[0][1]);
        a[0][2] = fdot2h(p00, wA.z, a[0][2]); a[0][3] = fdot2h(p00, wA.w, a[0][3]);
        a[0][0] = fdot2h(p01, wB.x, a[0][0]); a[0][1] = fdot2h(p01, wB.y, a[0][1]);
        a[0][2] = fdot2h(p01, wB.z, a[0][2]); a[0][3] = fdot2h(p01, wB.w, a[0][3]);
        a[1][0] = fdot2h(p10, wA.x, a[1][0]); a[1][1] = fdot2h(p10, wA.y, a[1][1]);
        a[1][2] = fdot2h(p10, wA.z, a[1][2]); a[1][3] = fdot2h(p10, wA.w, a[1][3]);
        a[1][0] = fdot2h(p11, wB.x, a[1][0]); a[1][1] = fdot2h(p11, wB.y, a[1][1]);
        a[1][2] = fdot2h(p11, wB.z, a[1][2]); a[1][3] = fdot2h(p11, wB.w, a[1][3]);
    }
#pragma unroll
    for (int k = 0; k < 2; k++) {
        float s = dinv[(size_t)c * N_NODES + v0 + k];
        uint2 pk = make_uint2(pack_half2(a[k][0] * s, a[k][1] * s),
                              pack_half2(a[k][2] * s, a[k][3] * s));
        *(uint2*)(h23 + ((size_t)c * N_NODES + v0 + k) * OUT_DIM + 4 * t) = pk;
    }
}

// ---------------- per-channel layer-1 gather -> e_c fp16 (phase-aligned sweep) -------
// One channel per launch: all resident threads sweep ONE 6.4MB slab monotonically
// (row-sorted CSR) -> instantaneous footprint ~1.4MB << 4MB per-XCD L2.

__global__ void gather_e_kernel(const int* __restrict__ row_ptr,
                                const u32* __restrict__ csr,
                                const u16* __restrict__ h3,
                                const float* __restrict__ dinv,
                                const float* __restrict__ bb,
                                u16* __restrict__ ebuf, int c) {
    int gid = blockIdx.x * blockDim.x + threadIdx.x;
    int v = gid >> 2;
    int t = gid & 3;
    if (v >= N_NODES) return;
    const u16* h = h3 + (size_t)c * N_NODES * HID_DIM;
    int beg = row_ptr[c * N_NODES + v], end = row_ptr[c * N_NODES + v + 1];
    float a[8];
#pragma unroll
    for (int k = 0; k < 8; k++) a[k] = 0.f;
    int ee = beg;
    for (; ee + 4 <= end; ee += 4) {
        u32 m0 = csr[ee], m1 = csr[ee + 1], m2 = csr[ee + 2], m3 = csr[ee + 3];
        uint4 u0 = *(const uint4*)(h + (size_t)(m0 & 0x1FFFF) * HID_DIM + 8 * t);
        uint4 u1 = *(const uint4*)(h + (size_t)(m1 & 0x1FFFF) * HID_DIM + 8 * t);
        uint4 u2 = *(const uint4*)(h + (size_t)(m2 & 0x1FFFF) * HID_DIM + 8 * t);
        uint4 u3 = *(const uint4*)(h + (size_t)(m3 & 0x1FFFF) * HID_DIM + 8 * t);
        float vl0 = val15(m0), vl1 = val15(m1), vl2 = val15(m2), vl3 = val15(m3);
        float2 f;
        f = unpack_half2(u0.x); a[0] += vl0 * f.x; a[1] += vl0 * f.y;
        f = unpack_half2(u0.y); a[2] += vl0 * f.x; a[3] += vl0 * f.y;
        f = unpack_half2(u0.z); a[4] += vl0 * f.x; a[5] += vl0 * f.y;
        f = unpack_half2(u0.w); a[6] += vl0 * f.x; a[7] += vl0 * f.y;
        f = unpack_half2(u1.x); a[0] += vl1 * f.x; a[1] += vl1 * f.y;
        f = unpack_half2(u1.y); a[2] += vl1 * f.x; a[3] += vl1 * f.y;
        f = unpack_half2(u1.z); a[4] += vl1 * f.x; a[5] += vl1 * f.y;
        f = unpack_half2(u1.w); a[6] += vl1 * f.x; a[7] += vl1 * f.y;
        f = unpack_half2(u2.x); a[0] += vl2 * f.x; a[1] += vl2 * f.y;
        f = unpack_half2(u2.y); a[2] += vl2 * f.x; a[3] += vl2 * f.y;
        f = unpack_half2(u2.z); a[4] += vl2 * f.x; a[5] += vl2 * f.y;
        f = unpack_half2(u2.w); a[6] += vl2 * f.x; a[7] += vl2 * f.y;
        f = unpack_half2(u3.x); a[0] += vl3 * f.x; a[1] += vl3 * f.y;
        f = unpack_half2(u3.y); a[2] += vl3 * f.x; a[3] += vl3 * f.y;
        f = unpack_half2(u3.z); a[4] += vl3 * f.x; a[5] += vl3 * f.y;
        f = unpack_half2(u3.w); a[6] += vl3 * f.x; a[7] += vl3 * f.y;
    }
    for (; ee < end; ee++) {
        u32 m = csr[ee];
        float vl = val15(m);
        uint4 u = *(const uint4*)(h + (size_t)(m & 0x1FFFF) * HID_DIM + 8 * t);
        float2 f;
        f = unpack_half2(u.x); a[0] += vl * f.x; a[1] += vl * f.y;
        f = unpack_half2(u.y); a[2] += vl * f.x; a[3] += vl * f.y;
        f = unpack_half2(u.z); a[4] += vl * f.x; a[5] += vl * f.y;
        f = unpack_half2(u.w); a[6] += vl * f.x; a[7] += vl * f.y;
    }
    float s = dinv[(size_t)c * N_NODES + v];   // self-loop: s^2*h[v] = s*h3s[v]
    uint4 u = *(const uint4*)(h + (size_t)v * HID_DIM + 8 * t);
    float2 f0 = unpack_half2(u.x), f1 = unpack_half2(u.y);
    float2 f2 = unpack_half2(u.z), f3 = unpack_half2(u.w);
    float4 bv0 = *(const float4*)(bb + t * 8);
    float4 bv1 = *(const float4*)(bb + t * 8 + 4);
    float e0 = fmaxf(a[0] + s * f0.x + bv0.x, 0.f);
    float e1 = fmaxf(a[1] + s * f0.y + bv0.y, 0.f);
    float e2 = fmaxf(a[2] + s * f1.x + bv0.z, 0.f);
    float e3 = fmaxf(a[3] + s * f1.y + bv0.w, 0.f);
    float e4 = fmaxf(a[4] + s * f2.x + bv1.x, 0.f);
    float e5 = fmaxf(a[5] + s * f2.y + bv1.y, 0.f);
    float e6 = fmaxf(a[6] + s * f3.x + bv1.z, 0.f);
    float e7 = fmaxf(a[7] + s * f3.y + bv1.w, 0.f);
    uint4 pk;
    pk.x = pack_half2(e0, e1); pk.y = pack_half2(e2, e3);
    pk.z = pack_half2(e4, e5); pk.w = pack_half2(e6, e7);
    *(uint4*)(ebuf + ((size_t)c * N_NODES + v) * HID_DIM + 8 * t) = pk;
}

// ---------------- attention combine: e[3] fp16 -> weights + hmix ----------------

__global__ void combine_kernel(const u16* __restrict__ ebuf,
                               const float* __restrict__ att_w,
                               float* __restrict__ hmix,
                               float* __restrict__ wout) {
    int gid = blockIdx.x * blockDim.x + threadIdx.x;
    int v = gid >> 2;
    int t = gid & 3;
    if (v >= N_NODES) return;
    float4 wv0 = *(const float4*)(att_w + t * 8);
    float4 wv1 = *(const float4*)(att_w + t * 8 + 4);
    float e[3][8];
    float coef[3];
#pragma unroll
    for (int c = 0; c < 3; c++) {
        uint4 u = *(const uint4*)(ebuf + ((size_t)c * N_NODES + v) * HID_DIM + 8 * t);
        float2 f0 = unpack_half2(u.x), f1 = unpack_half2(u.y);
        float2 f2 = unpack_half2(u.z), f3 = unpack_half2(u.w);
        e[c][0] = f0.x; e[c][1] = f0.y; e[c][2] = f1.x; e[c][3] = f1.y;
        e[c][4] = f2.x; e[c][5] = f2.y; e[c][6] = f3.x; e[c][7] = f3.y;
        float dot = e[c][0] * wv0.x + e[c][1] * wv0.y + e[c][2] * wv0.z + e[c][3] * wv0.w
                  + e[c][4] * wv1.x + e[c][5] * wv1.y + e[c][6] * wv1.z + e[c][7] * wv1.w;
        dot += __shfl_xor(dot, 1, 64);
        dot += __shfl_xor(dot, 2, 64);   // all 4 lanes of the group hold the full dot
        float lr = (dot > 0.0f) ? dot : 0.01f * dot;
        coef[c] = expf(lr);
    }
    float inv = 1.0f / (coef[0] + coef[1] + coef[2]);
    float w0 = coef[0] * inv, w1 = coef[1] * inv, w2 = coef[2] * inv;
    if (t == 0) {
        wout[v] = w0;
        wout[N_NODES + v] = w1;
        wout[2 * N_NODES + v] = w2;
    }
    float4 r0, r1;
    r0.x = w0 * e[0][0] + w1 * e[1][0] + w2 * e[2][0];
    r0.y = w0 * e[0][1] + w1 * e[1][1] + w2 * e[2][1];
    r0.z = w0 * e[0][2] + w1 * e[1][2] + w2 * e[2][2];
    r0.w = w0 * e[0][3] + w1 * e[1][3] + w2 * e[2][3];
    r1.x = w0 * e[0][4] + w1 * e[1][4] + w2 * e[2][4];
    r1.y = w0 * e[0][5] + w1 * e[1][5] + w2 * e[2][5];
    r1.z = w0 * e[0][6] + w1 * e[1][6] + w2 * e[2][6];
    r1.w = w0 * e[0][7] + w1 * e[1][7] + w2 * e[2][7];
    *(float4*)(hmix + (size_t)v * HID_DIM + t * 8) = r0;
    *(float4*)(hmix + (size_t)v * HID_DIM + t * 8 + 4) = r1;
}

// ---------------- per-channel layer-2 gather (phase-aligned sweep) -> out ----------
// c==0: init with summed biases and store; c>0: read-modify-write accumulate.

__global__ void gather_out_c_kernel(const int* __restrict__ row_ptr,
                                    const u32* __restrict__ csr,
                                    const u16* __restrict__ h23,
                                    const float* __restrict__ dinv,
                                    const float* __restrict__ bo0,
                                    const float* __restrict__ bo1,
                                    const float* __restrict__ bo2,
                                    float* __restrict__ out, int c) {
    int gid = blockIdx.x * blockDim.x + threadIdx.x;
    int v = gid >> 2;
    int t = gid & 3;
    if (v >= N_NODES) return;
    float a[8];
    if (c == 0) {
        float4 p0 = *(const float4*)(bo0 + t * 8);
        float4 p1 = *(const float4*)(bo0 + t * 8 + 4);
        float4 q0 = *(const float4*)(bo1 + t * 8);
        float4 q1 = *(const float4*)(bo1 + t * 8 + 4);
        float4 s0 = *(const float4*)(bo2 + t * 8);
        float4 s1 = *(const float4*)(bo2 + t * 8 + 4);
        a[0] = p0.x + q0.x + s0.x; a[1] = p0.y + q0.y + s0.y;
        a[2] = p0.z + q0.z + s0.z; a[3] = p0.w + q0.w + s0.w;
        a[4] = p1.x + q1.x + s1.x; a[5] = p1.y + q1.y + s1.y;
        a[6] = p1.z + q1.z + s1.z; a[7] = p1.w + q1.w + s1.w;
    } else {
#pragma unroll
        for (int k = 0; k < 8; k++) a[k] = 0.f;
    }
    const u16* h2m = h23 + (size_t)c * N_NODES * OUT_DIM;
    int beg = row_ptr[c * N_NODES + v], end = row_ptr[c * N_NODES + v + 1];
    int ee = beg;
    for (; ee + 4 <= end; ee += 4) {
        u32 m0 = csr[ee], m1 = csr[ee + 1], m2 = csr[ee + 2], m3 = csr[ee + 3];
        uint4 u0 = *(const uint4*)(h2m + (size_t)(m0 & 0x1FFFF) * OUT_DIM + 8 * t);
        uint4 u1 = *(const uint4*)(h2m + (size_t)(m1 & 0x1FFFF) * OUT_DIM + 8 * t);
        uint4 u2 = *(const uint4*)(h2m + (size_t)(m2 & 0x1FFFF) * OUT_DIM + 8 * t);
        uint4 u3 = *(const uint4*)(h2m + (size_t)(m3 & 0x1FFFF) * OUT_DIM + 8 * t);
        float vl0 = val15(m0), vl1 = val15(m1), vl2 = val15(m2), vl3 = val15(m3);
        float2 f;
        f = unpack_half2(u0.x); a[0] += vl0 * f.x; a[1] += vl0 * f.y;
        f = unpack_half2(u0.y); a[2] += vl0 * f.x; a[3] += vl0 * f.y;
        f = unpack_half2(u0.z); a[4] += vl0 * f.x; a[5] += vl0 * f.y;
        f = unpack_half2(u0.w); a[6] += vl0 * f.x; a[7] += vl0 * f.y;
        f = unpack_half2(u1.x); a[0] += vl1 * f.x; a[1] += vl1 * f.y;
        f = unpack_half2(u1.y); a[2] += vl1 * f.x; a[3] += vl1 * f.y;
        f = unpack_half2(u1.z); a[4] += vl1 * f.x; a[5] += vl1 * f.y;
        f = unpack_half2(u1.w); a[6] += vl1 * f.x; a[7] += vl1 * f.y;
        f = unpack_half2(u2.x); a[0] += vl2 * f.x; a[1] += vl2 * f.y;
        f = unpack_half2(u2.y); a[2] += vl2 * f.x; a[3] += vl2 * f.y;
        f = unpack_half2(u2.z); a[4] += vl2 * f.x; a[5] += vl2 * f.y;
        f = unpack_half2(u2.w); a[6] += vl2 * f.x; a[7] += vl2 * f.y;
        f = unpack_half2(u3.x); a[0] += vl3 * f.x; a[1] += vl3 * f.y;
        f = unpack_half2(u3.y); a[2] += vl3 * f.x; a[3] += vl3 * f.y;
        f = unpack_half2(u3.z); a[4] += vl3 * f.x; a[5] += vl3 * f.y;
        f = unpack_half2(u3.w); a[6] += vl3 * f.x; a[7] += vl3 * f.y;
    }
    for (; ee < end; ee++) {
        u32 m = csr[ee];
        float vl = val15(m);
        uint4 u = *(const uint4*)(h2m + (size_t)(m & 0x1FFFF) * OUT_DIM + 8 * t);
        float2 f;
        f = unpack_half2(u.x); a[0] += vl * f.x; a[1] += vl * f.y;
        f = unpack_half2(u.y); a[2] += vl * f.x; a[3] += vl * f.y;
        f = unpack_half2(u.z); a[4] += vl * f.x; a[5] += vl * f.y;
        f = unpack_half2(u.w); a[6] += vl * f.x; a[7] += vl * f.y;
    }
    float s = dinv[(size_t)c * N_NODES + v];   // self-loop: s*h23s[v]
    uint4 u = *(const uint4*)(h2m + (size_t)v * OUT_DIM + 8 * t);
    float2 f0 = unpack_half2(u.x), f1 = unpack_half2(u.y);
    float2 f2 = unpack_half2(u.z), f3 = unpack_half2(u.w);
    a[0] += s * f0.x; a[1] += s * f0.y; a[2] += s * f1.x; a[3] += s * f1.y;
    a[4] += s * f2.x; a[5] += s * f2.y; a[6] += s * f3.x; a[7] += s * f3.y;
    float* op = out + (size_t)v * OUT_DIM + t * 8;
    if (c == 0) {
        float4 o0, o1;
        o0.x = a[0]; o0.y = a[1]; o0.z = a[2]; o0.w = a[3];
        o1.x = a[4]; o1.y = a[5]; o1.z = a[6]; o1.w = a[7];
        *(float4*)(op) = o0;
        *(float4*)(op + 4) = o1;
    } else {
        float4 c0 = *(const float4*)(op);
        float4 c1 = *(const float4*)(op + 4);
        c0.x += a[0]; c0.y += a[1]; c0.z += a[2]; c0.w += a[3];
        c1.x += a[4]; c1.y += a[5]; c1.z += a[6]; c1.w += a[7];
        *(float4*)(op) = c0;
        *(float4*)(op + 4) = c1;
    }
}

// ---------------- launch ----------------

extern "C" void kernel_launch(void* const* d_in, const int* in_sizes, int n_in,
                              void* d_out, int out_size, void* d_ws, size_t ws_size,
                              hipStream_t stream) {
    const float* x[3];  const int* ei[3];  const float* ea[3];
    const float* W[3];  const float* b[3]; const float* Wo[3]; const float* bo[3];
    for (int c = 0; c < 3; c++) {
        x[c]  = (const float*)d_in[7 * c + 0];
        ei[c] = (const int*)  d_in[7 * c + 1];
        ea[c] = (const float*)d_in[7 * c + 2];
        W[c]  = (const float*)d_in[7 * c + 3];
        b[c]  = (const float*)d_in[7 * c + 4];
        Wo[c] = (const float*)d_in[7 * c + 5];
        bo[c] = (const float*)d_in[7 * c + 6];
    }
    const float* att_w = (const float*)d_in[21];
    float* out = (float*)d_out;                 // [N*32] then 3x [N] weights
    float* wout = out + (size_t)N_NODES * OUT_DIM;

    // workspace layout (4-byte units) — total 92.0 MB (same as proven round-0 layout)
    int*   wsb      = (int*)d_ws;
    float* dinv     = (float*)wsb;                            // 3N
    int*   row_ptr  = wsb + 3 * N_NODES;                      // 3N+1 (+3 pad)
    int*   blocksum = row_ptr + 3 * N_NODES + 4;              // 512
    size_t stg_off  = (size_t)(3 * N_NODES + 3 * N_NODES + 4 + 512);
    stg_off = (stg_off + 3) & ~(size_t)3;                     // 16B align
    int2*  stg      = (int2*)(wsb + stg_off);                 // 3E int2 (38.4 MB)
    u32*   csr      = (u32*)(stg + 3 * (size_t)N_EDGES);      // 3E u32 (19.2 MB)
    u16*   hA       = (u16*)(csr + 3 * (size_t)N_EDGES);      // 3*N*32 fp16 (19.2 MB)
    // hist_t/rp1 alias hA: dead before matmul_in3 writes h3 (1.3 MB < 19.2 MB)
    int*   hist_t   = (int*)hA;                               // SC_N
    int*   rp1      = hist_t + SC_N;                          // SC_N+1
    float* hmix     = (float*)(hA + 3 * (size_t)N_NODES * HID_DIM); // N*32 fp32
    u16*   ebuf     = (u16*)stg;                              // e[3][N][32] fp16 (19.2 MB)
    // ebuf aliases stg: stg dead after bucket_sort

    const int B = 256;

    // CSR build: hist -> scan(2 kernels) -> bin -> per-bucket row-sorted counting sort
    binhist_kernel<<<PB, BINB, 0, stream>>>(ei[0], ei[1], ei[2], hist_t);
    scan1_kernel<<<SC_G, B, 0, stream>>>(hist_t, rp1, blocksum);
    scan2_kernel<<<1, B, 0, stream>>>(blocksum, SC_G);
    binscatter_kernel<<<PB, BINB, 0, stream>>>(ei[0], ei[1], ei[2], ea[0], ea[1], ea[2],
                                               rp1, blocksum, stg);
    bucket_sort_kernel<<<NBT, B, 0, stream>>>(stg, rp1, blocksum, csr, dinv, row_ptr);

    // layer 1: matmul, then 3 channel-sequential gathers (phase-aligned) + combine
    matmul_in3_kernel<<<3 * MM2, B, 0, stream>>>(x[0], x[1], x[2], W[0], W[1], W[2],
                                                 dinv, hA);
    for (int c = 0; c < 3; c++)
        gather_e_kernel<<<GN4, B, 0, stream>>>(row_ptr, csr, hA, dinv, b[c], ebuf, c);
    combine_kernel<<<GN4, B, 0, stream>>>(ebuf, att_w, hmix, wout);

    // layer 2: matmul (h3 dead -> h23 reuses hA), 3 channel-sequential gathers -> out
    matmul_hid3_kernel<<<3 * MM2, B, 0, stream>>>(hmix, Wo[0], Wo[1], Wo[2], dinv, hA);
    for (int c = 0; c < 3; c++)
        gather_out_c_kernel<<<GN4, B, 0, stream>>>(row_ptr, csr, hA, dinv,
                                                   bo[0], bo[1], bo[2], out, c);
}

// Round 11
// 555.528 us; speedup vs baseline: 1.1354x; 1.0087x over previous
//
#include <hip/hip_runtime.h>
#include <hip/hip_fp16.h>

typedef unsigned short u16;
typedef unsigned int   u32;
typedef _Float16 h2 __attribute__((ext_vector_type(2)));

#define N_NODES 100000
#define N_EDGES 1600000
#define IN_DIM  128
#define HID_DIM 32
#define OUT_DIM 32

#define BK   512                 // cols per bucket (512 -> 256B scatter runs)
#define NBC  196                 // buckets per channel = ceil(100000/512)
#define NBT  (3 * NBC)           // 588 total buckets

#define PB    256                // binning blocks = 1 per CU (3E = 256*18750 exactly)
#define BINB  1024               // binning block size (16 waves)
#define CHUNK 18750              // edges per binning block
#define SC_N  (NBT * PB)         // 150528 scan elements (multiple of 8)
#define SC_CHUNK 2048
#define SC_G  ((SC_N + SC_CHUNK - 1) / SC_CHUNK)   // 74
#define GN4  ((N_NODES * 4 + 255) / 256) // 1563 blocks for 4-threads-per-node kernels
#define MM2  ((N_NODES + 63) / 64)       // 1563 matmul blocks/channel (64 nodes/block)

#define KEYB 4                   // row-bucket bits: row>>13 in 0..12 (fits 4 bits)
#define NKEY (BK << KEYB)        // 8192 sort keys: (cl<<4) | (row>>13)

// final ofs value without materializing scan3: ofs(m) = m ? rp1[m] + bs[(m-1)>>11] : 0
__device__ inline int ofs_at(const int* __restrict__ rp1, const int* __restrict__ bs, int m) {
    return m ? rp1[m] + bs[(m - 1) >> 11] : 0;
}

// ---------------- phase 1: per-block bucket histogram ----------------

__global__ void binhist_kernel(const int* __restrict__ ei0, const int* __restrict__ ei1,
                               const int* __restrict__ ei2, int* __restrict__ hist_t) {
    __shared__ int hloc[NBT];
    for (int i = threadIdx.x; i < NBT; i += blockDim.x) hloc[i] = 0;
    __syncthreads();
    int b = blockIdx.x;
    int beg = b * CHUNK, end = beg + CHUNK;
    for (int e = beg + threadIdx.x; e < end; e += blockDim.x) {
        int c = (e >= 2 * N_EDGES) ? 2 : (e >= N_EDGES ? 1 : 0);
        const int* ei = (c == 0) ? ei0 : (c == 1) ? ei1 : ei2;
        int col = ei[N_EDGES + (e - c * N_EDGES)];
        atomicAdd(&hloc[c * NBC + (col >> 9)], 1);
    }
    __syncthreads();
    for (int g = threadIdx.x; g < NBT; g += blockDim.x)
        hist_t[g * PB + b] = hloc[g];
}

// ---------------- phase 2: 2-kernel scan over hist_t[SC_N] -> rp1 (+blocksum) ----

__global__ void scan1_kernel(const int* __restrict__ counts, int* __restrict__ rp1,
                             int* __restrict__ blocksum) {
    __shared__ int wsum[4];
    int tid = threadIdx.x;
    int base = blockIdx.x * SC_CHUNK + tid * 8;
    int vals[8];
    int tsum = 0;
    if (base < SC_N) {          // SC_N multiple of 8 -> all-or-nothing per thread
        int4 v0 = *(const int4*)(counts + base);
        int4 v1 = *(const int4*)(counts + base + 4);
        vals[0] = v0.x; vals[1] = v0.y; vals[2] = v0.z; vals[3] = v0.w;
        vals[4] = v1.x; vals[5] = v1.y; vals[6] = v1.z; vals[7] = v1.w;
#pragma unroll
        for (int k = 0; k < 8; k++) tsum += vals[k];
    } else {
#pragma unroll
        for (int k = 0; k < 8; k++) vals[k] = 0;
    }
    int lane = tid & 63, wave = tid >> 6;
    int x = tsum;
    for (int d = 1; d < 64; d <<= 1) {
        int t = __shfl_up(x, d, 64);
        if (lane >= d) x += t;
    }
    if (lane == 63) wsum[wave] = x;
    __syncthreads();
    int woff = 0;
    for (int w = 0; w < wave; w++) woff += wsum[w];
    int run = woff + x - tsum;
    if (base < SC_N) {
#pragma unroll
        for (int k = 0; k < 8; k++) {
            run += vals[k];
            rp1[base + k + 1] = run;
        }
    }
    if (tid == blockDim.x - 1) blocksum[blockIdx.x] = woff + x;
    if (blockIdx.x == 0 && tid == 0) rp1[0] = 0;
}

// single block, loops over n entries in chunks of 256 with carry
__global__ void scan2_kernel(int* __restrict__ blocksum, int n) {
    __shared__ int wsum[4];
    int tid = threadIdx.x;
    int lane = tid & 63, wave = tid >> 6;
    int carry = 0;
    for (int base = 0; base < n; base += 256) {
        int i = base + tid;
        int v = (i < n) ? blocksum[i] : 0;
        int x = v;
        for (int d = 1; d < 64; d <<= 1) {
            int t = __shfl_up(x, d, 64);
            if (lane >= d) x += t;
        }
        if (lane == 63) wsum[wave] = x;
        __syncthreads();
        int woff = 0;
        for (int w = 0; w < wave; w++) woff += wsum[w];
        int total = wsum[0] + wsum[1] + wsum[2] + wsum[3];
        if (i < n) blocksum[i] = carry + woff + x - v;   // exclusive
        carry += total;
        __syncthreads();
    }
}

// ---------------- phase 3: binning scatter (no global atomics) ----------------
// entry: x = row | (colLow<<17) (9-bit colLow), y = ea bits (fp32)

__global__ void binscatter_kernel(const int* __restrict__ ei0, const int* __restrict__ ei1,
                                  const int* __restrict__ ei2,
                                  const float* __restrict__ ea0, const float* __restrict__ ea1,
                                  const float* __restrict__ ea2,
                                  const int* __restrict__ rp1, const int* __restrict__ bsum,
                                  int2* __restrict__ stg) {
    __shared__ int base_l[NBT];
    int b = blockIdx.x;
    for (int g = threadIdx.x; g < NBT; g += blockDim.x)
        base_l[g] = ofs_at(rp1, bsum, g * PB + b);
    __syncthreads();
    int beg = b * CHUNK, end = beg + CHUNK;
    for (int e = beg + threadIdx.x; e < end; e += blockDim.x) {
        int c = (e >= 2 * N_EDGES) ? 2 : (e >= N_EDGES ? 1 : 0);
        int le = e - c * N_EDGES;
        const int* ei = (c == 0) ? ei0 : (c == 1) ? ei1 : ei2;
        const float* ea = (c == 0) ? ea0 : (c == 1) ? ea1 : ea2;
        int row = ei[le];
        int col = ei[N_EDGES + le];
        int g = c * NBC + (col >> 9);
        int slot = atomicAdd(&base_l[g], 1);   // LDS atomic, block-local
        stg[slot] = make_int2(row | ((col & 511) << 17), __float_as_int(ea[le]));
    }
}

// ---------------- phase 4: per-bucket counting sort -> packed CSR + dinv + row_ptr ----
// csr entry: row(17b) | fp16(ea*dinv[col]) sans sign bit (15b).
// Sort key = (cl<<4)|(row>>13): row-sorted within col -> gather L2-window locality.

__global__ void bucket_sort_kernel(const int2* __restrict__ stg, const int* __restrict__ rp1,
                                   const int* __restrict__ bsum,
                                   u32* __restrict__ csr,
                                   float* __restrict__ dinv, int* __restrict__ row_ptr) {
    __shared__ int hist[NKEY];         // 32 KB; prefix after scan, cursor in pass 2
    __shared__ int colStart[BK];       // 2 KB
    __shared__ float deg[BK];          // 2 KB
    __shared__ float dl[BK];           // 2 KB
    __shared__ int wsum[4];
    int tid = threadIdx.x;
    int g = blockIdx.x;
    int c = g / NBC;
    int colBase = (g % NBC) << 9;
    for (int i = tid; i < NKEY; i += 256) hist[i] = 0;
    deg[tid] = 1.0f;                   // self-loop
    deg[tid + 256] = 1.0f;
    __syncthreads();
    int beg = ofs_at(rp1, bsum, g * PB);
    int end = (g == NBT - 1) ? 3 * N_EDGES : ofs_at(rp1, bsum, (g + 1) * PB);
    int cnt = end - beg;
    // pass 1: count keys + accumulate deg
    for (int i = tid; i < cnt; i += blockDim.x) {
        int2 p = stg[beg + i];
        int cl = (p.x >> 17) & 511;
        int row = p.x & 0x1FFFF;
        atomicAdd(&hist[(cl << KEYB) | (row >> 13)], 1);
        atomicAdd(&deg[cl], __int_as_float(p.y));
    }
    __syncthreads();
    // exclusive scan of hist[8192] in place (32 entries = 2 cols per thread)
    int base32 = tid * 32;
    int v[32]; int tsum = 0;
#pragma unroll
    for (int k = 0; k < 32; k++) { v[k] = hist[base32 + k]; tsum += v[k]; }
    int lane = tid & 63, wave = tid >> 6;
    int xs = tsum;
    for (int d = 1; d < 64; d <<= 1) {
        int tt = __shfl_up(xs, d, 64);
        if (lane >= d) xs += tt;
    }
    if (lane == 63) wsum[wave] = xs;
    __syncthreads();
    int woff = 0;
    for (int w = 0; w < wave; w++) woff += wsum[w];
    int run = woff + xs - tsum;        // exclusive prefix of this thread's first key
#pragma unroll
    for (int k = 0; k < 32; k++) {
        if (k == 0)  colStart[2 * tid]     = run;   // start of col 2*tid
        if (k == 16) colStart[2 * tid + 1] = run;   // start of col 2*tid+1
        int t2 = v[k]; hist[base32 + k] = run; run += t2;
    }
    dl[tid] = rsqrtf(deg[tid]);        // deg >= 1
    dl[tid + 256] = rsqrtf(deg[tid + 256]);
    __syncthreads();                   // prefix + colStart + dl visible to all
    // pass 2: re-read stg (cache-hot), scatter to final csr slot via cursor
    for (int i = tid; i < cnt; i += blockDim.x) {
        int2 p = stg[beg + i];
        int cl = (p.x >> 17) & 511;
        int row = p.x & 0x1FFFF;
        int key = (cl << KEYB) | (row >> 13);
        int slot = atomicAdd(&hist[key], 1);
        float vv = __int_as_float(p.y) * dl[cl];  // in [0,1): fp16 sign bit = 0
        __half h = __float2half(vv);
        u32 hb = (u32)(*(u16*)&h) & 0x7FFF;
        csr[beg + slot] = (u32)row | (hb << 17);
    }
#pragma unroll
    for (int q = 0; q < 2; q++) {
        int cl = tid + q * 256;
        int col = colBase + cl;
        if (col < N_NODES) {
            dinv[(size_t)c * N_NODES + col] = dl[cl];
            row_ptr[(size_t)c * N_NODES + col] = beg + colStart[cl];
        }
    }
    if (g == NBT - 1 && tid == 0) row_ptr[3 * N_NODES] = 3 * N_EDGES;
}

// ---------------- fp16 helpers ----------------

__device__ inline u32 pack_half2(float a, float b) {
    __half2 h = __floats2half2_rn(a, b);
    union { __half2 h; u32 u; } cv; cv.h = h;
    return cv.u;
}

__device__ inline float2 unpack_half2(u32 u) {
    union { u32 u; __half2 h; } cv; cv.u = u;
    return __half22float2(cv.h);
}

__device__ inline float val15(u32 meta) {       // decode 15-bit fp16 payload
    return unpack_half2(meta >> 17).x;          // high half = 0, ignored
}

// v_dot2_f32_f16: a.x*b.x + a.y*b.y + c, fp32 accumulate (f16 products exact in f32)
__device__ inline float fdot2h(u32 a, u32 b, float c) {
    union { u32 u; h2 h; } ca, cb; ca.u = a; cb.u = b;
    return __builtin_amdgcn_fdot2(ca.h, cb.h, c, false);
}

// ---------------- matmul (3 channels): x_c[N,128] @ W_c[128,32], scale by dinv, fp16 ----
// x tile staged via LDS with fully-coalesced float4 loads (was: 8-lane broadcast loads
// = 128B useful per VMEM instr -> VMEM-latency-bound at 80us). fp16 conversion done
// once per element (was 8x redundant). Xs row stride 66 u32: 8B-aligned rows,
// group-stride 4 banks -> conflict-free b64 reads.

__global__ void matmul_in3_kernel(const float* __restrict__ x0, const float* __restrict__ x1,
                                  const float* __restrict__ x2,
                                  const float* __restrict__ W0, const float* __restrict__ W1,
                                  const float* __restrict__ W2,
                                  const float* __restrict__ dinv,
                                  u16* __restrict__ h3) {
    __shared__ u32 Ws2[(IN_DIM / 2) * HID_DIM];   // 8 KB: [jp][d] = half2(W[2jp][d],W[2jp+1][d])
    __shared__ u32 Xs[64][66];                    // 16.9 KB: [node][jp] fp16 pairs, pad 2
    int c = blockIdx.x / MM2;
    int lb = blockIdx.x % MM2;
    const float* x = (c == 0) ? x0 : (c == 1) ? x1 : x2;
    const float* W = (c == 0) ? W0 : (c == 1) ? W1 : W2;
    for (int i = threadIdx.x; i < (IN_DIM / 2) * HID_DIM; i += blockDim.x) {
        int d = i & 31, jp = i >> 5;
        Ws2[i] = pack_half2(W[(2 * jp) * HID_DIM + d], W[(2 * jp + 1) * HID_DIM + d]);
    }
    int v_base = lb * 64;
    const float* xbase = x + (size_t)v_base * IN_DIM;
    for (int i = threadIdx.x; i < 2048; i += blockDim.x) {   // 2048 float4s = 64x128 f32
        int node = i >> 5;                // (4i)/128
        if (v_base + node < N_NODES) {
            float4 xv = *(const float4*)(xbase + 4 * i);
            int jp = (4 * i & 127) >> 1;  // even
            *(uint2*)&Xs[node][jp] = make_uint2(pack_half2(xv.x, xv.y),
                                                pack_half2(xv.z, xv.w));
        }
    }
    __syncthreads();
    int t = threadIdx.x & 7;          // output dim slice 4t..4t+3
    int grp = threadIdx.x >> 3;       // 0..31
    int v0 = v_base + grp * 2;        // 2 consecutive nodes
    if (v0 >= N_NODES) return;        // N_NODES even -> all-or-nothing per thread
    float a[2][4];
#pragma unroll
    for (int k = 0; k < 2; k++)
#pragma unroll
        for (int d = 0; d < 4; d++) a[k][d] = 0.f;
#pragma unroll 4
    for (int q = 0; q < 32; q++) {    // 4 K per iter (jp = 2q, 2q+1)
        uint2 xq0 = *(const uint2*)&Xs[2 * grp][2 * q];
        uint2 xq1 = *(const uint2*)&Xs[2 * grp + 1][2 * q];
        uint4 wA = *(const uint4*)&Ws2[(2 * q) * HID_DIM + 4 * t];
        uint4 wB = *(const uint4*)&Ws2[(2 * q + 1) * HID_DIM + 4 * t];
        a[0][0] = fdot2h(xq0.x, wA.x, a[0][0]); a[0][1] = fdot2h(xq0.x, wA.y, a[0][1]);
        a[0][2] = fdot2h(xq0.x, wA.z, a[0][2]); a[0][3] = fdot2h(xq0.x, wA.w, a[0][3]);
        a[0][0] = fdot2h(xq0.y, wB.x, a[0][0]); a[0][1] = fdot2h(xq0.y, wB.y, a[0][1]);
        a[0][2] = fdot2h(xq0.y, wB.z, a[0][2]); a[0][3] = fdot2h(xq0.y, wB.w, a[0][3]);
        a[1][0] = fdot2h(xq1.x, wA.x, a[1][0]); a[1][1] = fdot2h(xq1.x, wA.y, a[1][1]);
        a[1][2] = fdot2h(xq1.x, wA.z, a[1][2]); a[1][3] = fdot2h(xq1.x, wA.w, a[1][3]);
        a[1][0] = fdot2h(xq1.y, wB.x, a[1][0]); a[1][1] = fdot2h(xq1.y, wB.y, a[1][1]);
        a[1][2] = fdot2h(xq1.y, wB.z, a[1][2]); a[1][3] = fdot2h(xq1.y, wB.w, a[1][3]);
    }
#pragma unroll
    for (int k = 0; k < 2; k++) {
        float s = dinv[(size_t)c * N_NODES + v0 + k];
        uint2 pk = make_uint2(pack_half2(a[k][0] * s, a[k][1] * s),
                              pack_half2(a[k][2] * s, a[k][3] * s));
        *(uint2*)(h3 + ((size_t)c * N_NODES + v0 + k) * HID_DIM + 4 * t) = pk;
    }
}

// ---------------- matmul (3 channels): hmix[N,32] @ Wo_c[32,32], scale by dinv, fp16 ----
// same LDS-staged structure

__global__ void matmul_hid3_kernel(const float* __restrict__ hmix,
                                   const float* __restrict__ Wo0, const float* __restrict__ Wo1,
                                   const float* __restrict__ Wo2,
                                   const float* __restrict__ dinv,
                                   u16* __restrict__ h23) {
    __shared__ u32 Ws2[(HID_DIM / 2) * OUT_DIM];  // 2 KB
    __shared__ u32 Xs[64][18];                    // 4.6 KB: [node][jp], pad 2
    int c = blockIdx.x / MM2;
    int lb = blockIdx.x % MM2;
    const float* Wo = (c == 0) ? Wo0 : (c == 1) ? Wo1 : Wo2;
    for (int i = threadIdx.x; i < (HID_DIM / 2) * OUT_DIM; i += blockDim.x) {
        int d = i & 31, jp = i >> 5;
        Ws2[i] = pack_half2(Wo[(2 * jp) * OUT_DIM + d], Wo[(2 * jp + 1) * OUT_DIM + d]);
    }
    int v_base = lb * 64;
    const float* hbase = hmix + (size_t)v_base * HID_DIM;
    for (int i = threadIdx.x; i < 512; i += blockDim.x) {    // 512 float4s = 64x32 f32
        int node = i >> 3;                // (4i)/32
        if (v_base + node < N_NODES) {
            float4 xv = *(const float4*)(hbase + 4 * i);
            int jp = (4 * i & 31) >> 1;   // even
            *(uint2*)&Xs[node][jp] = make_uint2(pack_half2(xv.x, xv.y),
                                                pack_half2(xv.z, xv.w));
        }
    }
    __syncthreads();
    int t = threadIdx.x & 7;
    int grp = threadIdx.x >> 3;
    int v0 = v_base + grp * 2;
    if (v0 >= N_NODES) return;
    float a[2][4];
#pragma unroll
    for (int k = 0; k < 2; k++)
#pragma unroll
        for (int d = 0; d < 4; d++) a[k][d] = 0.f;
#pragma unroll
    for (int q = 0; q < 8; q++) {
        uint2 xq0 = *(const uint2*)&Xs[2 * grp][2 * q];
        uint2 xq1 = *(const uint2*)&Xs[2 * grp + 1][2 * q];
        uint4 wA = *(const uint4*)&Ws2[(2 * q) * OUT_DIM + 4 * t];
        uint4 wB = *(const uint4*)&Ws2[(2 * q + 1) * OUT_DIM + 4 * t];
        a[0][0] = fdot2h(xq0.x, wA.x, a[0][0]); a[0][1] = fdot2h(xq0.x, wA.y, a[0][1]);
        a[0][2] = fdot2h(xq0.x, wA.z, a[0][2]); a[0][3] = fdot2h(xq0.x, wA.w, a[0][3]);
        a[0][0] = fdot2h(xq0.y, wB.x, a[0][0]); a[0][1] = fdot2h(xq0.y, wB.y, a[0][1]);
        a[0][2] = fdot2h(xq0.y, wB.z, a[0][2]); a[0][3] = fdot2h(xq0.y, wB.w, a[0][3]);
        a[1][0] = fdot2h(xq1.x, wA.x, a[1][0]); a[1][1] = fdot2h(xq1.x, wA.y, a[1][1]);
        a[1][2] = fdot2h(xq1.x, wA.z, a[1][2]); a[1][3] = fdot2h(xq1.x, wA.w, a[1][3]);
        a[1][0] = fdot2h(xq1.y, wB.x, a[1][0]); a[1][1] = fdot2h(xq1.y, wB.y, a[1][1]);
        a[1][2] = fdot2h(xq1.y, wB.z, a[1][2]); a[1][3] = fdot2h(xq1.y, wB.w, a[1][3]);
    }
#pragma unroll
    for (int k = 0; k < 2; k++) {
        float s = dinv[(size_t)c * N_NODES + v0 + k];
        uint2 pk = make_uint2(pack_half2(a[k][0] * s, a[k][1] * s),
                              pack_half2(a[k][2] * s, a[k][3] * s));
        *(uint2*)(h23 + ((size_t)c * N_NODES + v0 + k) * OUT_DIM + 4 * t) = pk;
    }
}

// ---------------- per-channel layer-1 gather -> e_c fp16 (phase-aligned sweep) -------

__global__ void gather_e_kernel(const int* __restrict__ row_ptr,
                                const u32* __restrict__ csr,
                                const u16* __restrict__ h3,
                                const float* __restrict__ dinv,
                                const float* __restrict__ bb,
                                u16* __restrict__ ebuf, int c) {
    int gid = blockIdx.x * blockDim.x + threadIdx.x;
    int v = gid >> 2;
    int t = gid & 3;
    if (v >= N_NODES) return;
    const u16* h = h3 + (size_t)c * N_NODES * HID_DIM;
    int beg = row_ptr[c * N_NODES + v], end = row_ptr[c * N_NODES + v + 1];
    float a[8];
#pragma unroll
    for (int k = 0; k < 8; k++) a[k] = 0.f;
    int ee = beg;
    for (; ee + 4 <= end; ee += 4) {
        u32 m0 = csr[ee], m1 = csr[ee + 1], m2 = csr[ee + 2], m3 = csr[ee + 3];
        uint4 u0 = *(const uint4*)(h + (size_t)(m0 & 0x1FFFF) * HID_DIM + 8 * t);
        uint4 u1 = *(const uint4*)(h + (size_t)(m1 & 0x1FFFF) * HID_DIM + 8 * t);
        uint4 u2 = *(const uint4*)(h + (size_t)(m2 & 0x1FFFF) * HID_DIM + 8 * t);
        uint4 u3 = *(const uint4*)(h + (size_t)(m3 & 0x1FFFF) * HID_DIM + 8 * t);
        float vl0 = val15(m0), vl1 = val15(m1), vl2 = val15(m2), vl3 = val15(m3);
        float2 f;
        f = unpack_half2(u0.x); a[0] += vl0 * f.x; a[1] += vl0 * f.y;
        f = unpack_half2(u0.y); a[2] += vl0 * f.x; a[3] += vl0 * f.y;
        f = unpack_half2(u0.z); a[4] += vl0 * f.x; a[5] += vl0 * f.y;
        f = unpack_half2(u0.w); a[6] += vl0 * f.x; a[7] += vl0 * f.y;
        f = unpack_half2(u1.x); a[0] += vl1 * f.x; a[1] += vl1 * f.y;
        f = unpack_half2(u1.y); a[2] += vl1 * f.x; a[3] += vl1 * f.y;
        f = unpack_half2(u1.z); a[4] += vl1 * f.x; a[5] += vl1 * f.y;
        f = unpack_half2(u1.w); a[6] += vl1 * f.x; a[7] += vl1 * f.y;
        f = unpack_half2(u2.x); a[0] += vl2 * f.x; a[1] += vl2 * f.y;
        f = unpack_half2(u2.y); a[2] += vl2 * f.x; a[3] += vl2 * f.y;
        f = unpack_half2(u2.z); a[4] += vl2 * f.x; a[5] += vl2 * f.y;
        f = unpack_half2(u2.w); a[6] += vl2 * f.x; a[7] += vl2 * f.y;
        f = unpack_half2(u3.x); a[0] += vl3 * f.x; a[1] += vl3 * f.y;
        f = unpack_half2(u3.y); a[2] += vl3 * f.x; a[3] += vl3 * f.y;
        f = unpack_half2(u3.z); a[4] += vl3 * f.x; a[5] += vl3 * f.y;
        f = unpack_half2(u3.w); a[6] += vl3 * f.x; a[7] += vl3 * f.y;
    }
    for (; ee < end; ee++) {
        u32 m = csr[ee];
        float vl = val15(m);
        uint4 u = *(const uint4*)(h + (size_t)(m & 0x1FFFF) * HID_DIM + 8 * t);
        float2 f;
        f = unpack_half2(u.x); a[0] += vl * f.x; a[1] += vl * f.y;
        f = unpack_half2(u.y); a[2] += vl * f.x; a[3] += vl * f.y;
        f = unpack_half2(u.z); a[4] += vl * f.x; a[5] += vl * f.y;
        f = unpack_half2(u.w); a[6] += vl * f.x; a[7] += vl * f.y;
    }
    float s = dinv[(size_t)c * N_NODES + v];   // self-loop: s^2*h[v] = s*h3s[v]
    uint4 u = *(const uint4*)(h + (size_t)v * HID_DIM + 8 * t);
    float2 f0 = unpack_half2(u.x), f1 = unpack_half2(u.y);
    float2 f2 = unpack_half2(u.z), f3 = unpack_half2(u.w);
    float4 bv0 = *(const float4*)(bb + t * 8);
    float4 bv1 = *(const float4*)(bb + t * 8 + 4);
    float e0 = fmaxf(a[0] + s * f0.x + bv0.x, 0.f);
    float e1 = fmaxf(a[1] + s * f0.y + bv0.y, 0.f);
    float e2 = fmaxf(a[2] + s * f1.x + bv0.z, 0.f);
    float e3 = fmaxf(a[3] + s * f1.y + bv0.w, 0.f);
    float e4 = fmaxf(a[4] + s * f2.x + bv1.x, 0.f);
    float e5 = fmaxf(a[5] + s * f2.y + bv1.y, 0.f);
    float e6 = fmaxf(a[6] + s * f3.x + bv1.z, 0.f);
    float e7 = fmaxf(a[7] + s * f3.y + bv1.w, 0.f);
    uint4 pk;
    pk.x = pack_half2(e0, e1); pk.y = pack_half2(e2, e3);
    pk.z = pack_half2(e4, e5); pk.w = pack_half2(e6, e7);
    *(uint4*)(ebuf + ((size_t)c * N_NODES + v) * HID_DIM + 8 * t) = pk;
}

// ---------------- attention combine: e[3] fp16 -> weights + hmix ----------------

__global__ void combine_kernel(const u16* __restrict__ ebuf,
                               const float* __restrict__ att_w,
                               float* __restrict__ hmix,
                               float* __restrict__ wout) {
    int gid = blockIdx.x * blockDim.x + threadIdx.x;
    int v = gid >> 2;
    int t = gid & 3;
    if (v >= N_NODES) return;
    float4 wv0 = *(const float4*)(att_w + t * 8);
    float4 wv1 = *(const float4*)(att_w + t * 8 + 4);
    float e[3][8];
    float coef[3];
#pragma unroll
    for (int c = 0; c < 3; c++) {
        uint4 u = *(const uint4*)(ebuf + ((size_t)c * N_NODES + v) * HID_DIM + 8 * t);
        float2 f0 = unpack_half2(u.x), f1 = unpack_half2(u.y);
        float2 f2 = unpack_half2(u.z), f3 = unpack_half2(u.w);
        e[c][0] = f0.x; e[c][1] = f0.y; e[c][2] = f1.x; e[c][3] = f1.y;
        e[c][4] = f2.x; e[c][5] = f2.y; e[c][6] = f3.x; e[c][7] = f3.y;
        float dot = e[c][0] * wv0.x + e[c][1] * wv0.y + e[c][2] * wv0.z + e[c][3] * wv0.w
                  + e[c][4] * wv1.x + e[c][5] * wv1.y + e[c][6] * wv1.z + e[c][7] * wv1.w;
        dot += __shfl_xor(dot, 1, 64);
        dot += __shfl_xor(dot, 2, 64);   // all 4 lanes of the group hold the full dot
        float lr = (dot > 0.0f) ? dot : 0.01f * dot;
        coef[c] = expf(lr);
    }
    float inv = 1.0f / (coef[0] + coef[1] + coef[2]);
    float w0 = coef[0] * inv, w1 = coef[1] * inv, w2 = coef[2] * inv;
    if (t == 0) {
        wout[v] = w0;
        wout[N_NODES + v] = w1;
        wout[2 * N_NODES + v] = w2;
    }
    float4 r0, r1;
    r0.x = w0 * e[0][0] + w1 * e[1][0] + w2 * e[2][0];
    r0.y = w0 * e[0][1] + w1 * e[1][1] + w2 * e[2][1];
    r0.z = w0 * e[0][2] + w1 * e[1][2] + w2 * e[2][2];
    r0.w = w0 * e[0][3] + w1 * e[1][3] + w2 * e[2][3];
    r1.x = w0 * e[0][4] + w1 * e[1][4] + w2 * e[2][4];
    r1.y = w0 * e[0][5] + w1 * e[1][5] + w2 * e[2][5];
    r1.z = w0 * e[0][6] + w1 * e[1][6] + w2 * e[2][6];
    r1.w = w0 * e[0][7] + w1 * e[1][7] + w2 * e[2][7];
    *(float4*)(hmix + (size_t)v * HID_DIM + t * 8) = r0;
    *(float4*)(hmix + (size_t)v * HID_DIM + t * 8 + 4) = r1;
}

// ---------------- per-channel layer-2 gather (phase-aligned sweep) -> out ----------
// c==0: init with summed biases and store; c>0: read-modify-write accumulate.

__global__ void gather_out_c_kernel(const int* __restrict__ row_ptr,
                                    const u32* __restrict__ csr,
                                    const u16* __restrict__ h23,
                                    const float* __restrict__ dinv,
                                    const float* __restrict__ bo0,
                                    const float* __restrict__ bo1,
                                    const float* __restrict__ bo2,
                                    float* __restrict__ out, int c) {
    int gid = blockIdx.x * blockDim.x + threadIdx.x;
    int v = gid >> 2;
    int t = gid & 3;
    if (v >= N_NODES) return;
    float a[8];
    if (c == 0) {
        float4 p0 = *(const float4*)(bo0 + t * 8);
        float4 p1 = *(const float4*)(bo0 + t * 8 + 4);
        float4 q0 = *(const float4*)(bo1 + t * 8);
        float4 q1 = *(const float4*)(bo1 + t * 8 + 4);
        float4 s0 = *(const float4*)(bo2 + t * 8);
        float4 s1 = *(const float4*)(bo2 + t * 8 + 4);
        a[0] = p0.x + q0.x + s0.x; a[1] = p0.y + q0.y + s0.y;
        a[2] = p0.z + q0.z + s0.z; a[3] = p0.w + q0.w + s0.w;
        a[4] = p1.x + q1.x + s1.x; a[5] = p1.y + q1.y + s1.y;
        a[6] = p1.z + q1.z + s1.z; a[7] = p1.w + q1.w + s1.w;
    } else {
#pragma unroll
        for (int k = 0; k < 8; k++) a[k] = 0.f;
    }
    const u16* h2m = h23 + (size_t)c * N_NODES * OUT_DIM;
    int beg = row_ptr[c * N_NODES + v], end = row_ptr[c * N_NODES + v + 1];
    int ee = beg;
    for (; ee + 4 <= end; ee += 4) {
        u32 m0 = csr[ee], m1 = csr[ee + 1], m2 = csr[ee + 2], m3 = csr[ee + 3];
        uint4 u0 = *(const uint4*)(h2m + (size_t)(m0 & 0x1FFFF) * OUT_DIM + 8 * t);
        uint4 u1 = *(const uint4*)(h2m + (size_t)(m1 & 0x1FFFF) * OUT_DIM + 8 * t);
        uint4 u2 = *(const uint4*)(h2m + (size_t)(m2 & 0x1FFFF) * OUT_DIM + 8 * t);
        uint4 u3 = *(const uint4*)(h2m + (size_t)(m3 & 0x1FFFF) * OUT_DIM + 8 * t);
        float vl0 = val15(m0), vl1 = val15(m1), vl2 = val15(m2), vl3 = val15(m3);
        float2 f;
        f = unpack_half2(u0.x); a[0] += vl0 * f.x; a[1] += vl0 * f.y;
        f = unpack_half2(u0.y); a[2] += vl0 * f.x; a[3] += vl0 * f.y;
        f = unpack_half2(u0.z); a[4] += vl0 * f.x; a[5] += vl0 * f.y;
        f = unpack_half2(u0.w); a[6] += vl0 * f.x; a[7] += vl0 * f.y;
        f = unpack_half2(u1.x); a[0] += vl1 * f.x; a[1] += vl1 * f.y;
        f = unpack_half2(u1.y); a[2] += vl1 * f.x; a[3] += vl1 * f.y;
        f = unpack_half2(u1.z); a[4] += vl1 * f.x; a[5] += vl1 * f.y;
        f = unpack_half2(u1.w); a[6] += vl1 * f.x; a[7] += vl1 * f.y;
        f = unpack_half2(u2.x); a[0] += vl2 * f.x; a[1] += vl2 * f.y;
        f = unpack_half2(u2.y); a[2] += vl2 * f.x; a[3] += vl2 * f.y;
        f = unpack_half2(u2.z); a[4] += vl2 * f.x; a[5] += vl2 * f.y;
        f = unpack_half2(u2.w); a[6] += vl2 * f.x; a[7] += vl2 * f.y;
        f = unpack_half2(u3.x); a[0] += vl3 * f.x; a[1] += vl3 * f.y;
        f = unpack_half2(u3.y); a[2] += vl3 * f.x; a[3] += vl3 * f.y;
        f = unpack_half2(u3.z); a[4] += vl3 * f.x; a[5] += vl3 * f.y;
        f = unpack_half2(u3.w); a[6] += vl3 * f.x; a[7] += vl3 * f.y;
    }
    for (; ee < end; ee++) {
        u32 m = csr[ee];
        float vl = val15(m);
        uint4 u = *(const uint4*)(h2m + (size_t)(m & 0x1FFFF) * OUT_DIM + 8 * t);
        float2 f;
        f = unpack_half2(u.x); a[0] += vl * f.x; a[1] += vl * f.y;
        f = unpack_half2(u.y); a[2] += vl * f.x; a[3] += vl * f.y;
        f = unpack_half2(u.z); a[4] += vl * f.x; a[5] += vl * f.y;
        f = unpack_half2(u.w); a[6] += vl * f.x; a[7] += vl * f.y;
    }
    float s = dinv[(size_t)c * N_NODES + v];   // self-loop: s*h23s[v]
    uint4 u = *(const uint4*)(h2m + (size_t)v * OUT_DIM + 8 * t);
    float2 f0 = unpack_half2(u.x), f1 = unpack_half2(u.y);
    float2 f2 = unpack_half2(u.z), f3 = unpack_half2(u.w);
    a[0] += s * f0.x; a[1] += s * f0.y; a[2] += s * f1.x; a[3] += s * f1.y;
    a[4] += s * f2.x; a[5] += s * f2.y; a[6] += s * f3.x; a[7] += s * f3.y;
    float* op = out + (size_t)v * OUT_DIM + t * 8;
    if (c == 0) {
        float4 o0, o1;
        o0.x = a[0]; o0.y = a[1]; o0.z = a[2]; o0.w = a[3];
        o1.x = a[4]; o1.y = a[5]; o1.z = a[6]; o1.w = a[7];
        *(float4*)(op) = o0;
        *(float4*)(op + 4) = o1;
    } else {
        float4 c0 = *(const float4*)(op);
        float4 c1 = *(const float4*)(op + 4);
        c0.x += a[0]; c0.y += a[1]; c0.z += a[2]; c0.w += a[3];
        c1.x += a[4]; c1.y += a[5]; c1.z += a[6]; c1.w += a[7];
        *(float4*)(op) = c0;
        *(float4*)(op + 4) = c1;
    }
}

// ---------------- launch ----------------

extern "C" void kernel_launch(void* const* d_in, const int* in_sizes, int n_in,
                              void* d_out, int out_size, void* d_ws, size_t ws_size,
                              hipStream_t stream) {
    const float* x[3];  const int* ei[3];  const float* ea[3];
    const float* W[3];  const float* b[3]; const float* Wo[3]; const float* bo[3];
    for (int c = 0; c < 3; c++) {
        x[c]  = (const float*)d_in[7 * c + 0];
        ei[c] = (const int*)  d_in[7 * c + 1];
        ea[c] = (const float*)d_in[7 * c + 2];
        W[c]  = (const float*)d_in[7 * c + 3];
        b[c]  = (const float*)d_in[7 * c + 4];
        Wo[c] = (const float*)d_in[7 * c + 5];
        bo[c] = (const float*)d_in[7 * c + 6];
    }
    const float* att_w = (const float*)d_in[21];
    float* out = (float*)d_out;                 // [N*32] then 3x [N] weights
    float* wout = out + (size_t)N_NODES * OUT_DIM;

    // workspace layout (4-byte units) — total 92.0 MB (same as proven round-0 layout)
    int*   wsb      = (int*)d_ws;
    float* dinv     = (float*)wsb;                            // 3N
    int*   row_ptr  = wsb + 3 * N_NODES;                      // 3N+1 (+3 pad)
    int*   blocksum = row_ptr + 3 * N_NODES + 4;              // 512
    size_t stg_off  = (size_t)(3 * N_NODES + 3 * N_NODES + 4 + 512);
    stg_off = (stg_off + 3) & ~(size_t)3;                     // 16B align
    int2*  stg      = (int2*)(wsb + stg_off);                 // 3E int2 (38.4 MB)
    u32*   csr      = (u32*)(stg + 3 * (size_t)N_EDGES);      // 3E u32 (19.2 MB)
    u16*   hA       = (u16*)(csr + 3 * (size_t)N_EDGES);      // 3*N*32 fp16 (19.2 MB)
    // hist_t/rp1 alias hA: dead before matmul_in3 writes h3 (1.3 MB < 19.2 MB)
    int*   hist_t   = (int*)hA;                               // SC_N
    int*   rp1      = hist_t + SC_N;                          // SC_N+1
    float* hmix     = (float*)(hA + 3 * (size_t)N_NODES * HID_DIM); // N*32 fp32
    u16*   ebuf     = (u16*)stg;                              // e[3][N][32] fp16 (19.2 MB)
    // ebuf aliases stg: stg dead after bucket_sort

    const int B = 256;

    // CSR build: hist -> scan(2 kernels) -> bin -> per-bucket row-sorted counting sort
    binhist_kernel<<<PB, BINB, 0, stream>>>(ei[0], ei[1], ei[2], hist_t);
    scan1_kernel<<<SC_G, B, 0, stream>>>(hist_t, rp1, blocksum);
    scan2_kernel<<<1, B, 0, stream>>>(blocksum, SC_G);
    binscatter_kernel<<<PB, BINB, 0, stream>>>(ei[0], ei[1], ei[2], ea[0], ea[1], ea[2],
                                               rp1, blocksum, stg);
    bucket_sort_kernel<<<NBT, B, 0, stream>>>(stg, rp1, blocksum, csr, dinv, row_ptr);

    // layer 1: matmul (LDS-staged x), 3 channel-sequential gathers + combine
    matmul_in3_kernel<<<3 * MM2, B, 0, stream>>>(x[0], x[1], x[2], W[0], W[1], W[2],
                                                 dinv, hA);
    for (int c = 0; c < 3; c++)
        gather_e_kernel<<<GN4, B, 0, stream>>>(row_ptr, csr, hA, dinv, b[c], ebuf, c);
    combine_kernel<<<GN4, B, 0, stream>>>(ebuf, att_w, hmix, wout);

    // layer 2: matmul (h3 dead -> h23 reuses hA), 3 channel-sequential gathers -> out
    matmul_hid3_kernel<<<3 * MM2, B, 0, stream>>>(hmix, Wo[0], Wo[1], Wo[2], dinv, hA);
    for (int c = 0; c < 3; c++)
        gather_out_c_kernel<<<GN4, B, 0, stream>>>(row_ptr, csr, hA, dinv,
                                                   bo[0], bo[1], bo[2], out, c);
}